// Round 7
// baseline (469.945 us; speedup 1.0000x reference)
//
#include <hip/hip_runtime.h>

// ---------------------------------------------------------------------------
// PAM_Module_Dep: dual-modality position attention. B=4, C=512, N=4096, CQ=64.
// Round 12: proj W-fragment batch prefetch (attn unchanged from round 10).
//   Round-11 evidence: coalesced stores + occupancy 3.4x + conflicts /9 all
//   landed (WRITE_SIZE 38->32MB clean, Occ 23.5%) yet proj dur UNCHANGED
//   229us -> binding constraint is a serial latency chain: 96 dependent
//   global W-load->MFMA pairs per wave (VGPR 88 = shallow overlap).
// Fix: preload all 16(+16) W fragments per tile into registers in ONE
//   batched issue (static-index local arrays -> VGPRs; ~190 regs, under the
//   launch_bounds(512,2) cap of 256). 16-32 loads in flight, single drain,
//   then 96 MFMAs from regs+LDS.
// attn: producer/consumer wave specialization (r10): 4 energy waves + 8 PV
//   waves, 1 barrier/iter, counted vmcnt, P parity dbuf. attn math retained:
//   constant mhat=32, split-bf16 exact energy (hh+hl+lh), p rounded to bf16
//   with l summed from rounded p, O^T=V^T*P^T, out = gamma*O/l + x.
// ---------------------------------------------------------------------------

typedef __attribute__((ext_vector_type(8))) short bf16x8;
typedef __attribute__((ext_vector_type(4))) float f32x4;

__device__ __forceinline__ float bf2f(unsigned short u) {
  return __builtin_bit_cast(float, (unsigned int)u << 16);
}
__device__ __forceinline__ unsigned short f2bf(float f) {
  unsigned int u = __builtin_bit_cast(unsigned int, f);
  u = u + 0x7fffu + ((u >> 16) & 1u);   // RNE
  return (unsigned short)(u >> 16);
}
__device__ __forceinline__ float bflo(unsigned int u) {
  return __builtin_bit_cast(float, u << 16);
}

// Async 16B/lane global->LDS DMA (wave writes ldsbase + lane*16).
__device__ __forceinline__ void gld16(const char* g, char* l) {
  __builtin_amdgcn_global_load_lds(
      (const __attribute__((address_space(1))) unsigned int*)g,
      (__attribute__((address_space(3))) unsigned int*)l, 16, 0, 0);
}

// Returns 1 if x looks like fp32 data, 0 if bf16. Wave-uniform, deterministic.
__device__ __forceinline__ int detect_fp32_mode(const void* xv) {
  const unsigned int* p = (const unsigned int*)xv;
  const int lane = threadIdx.x & 63;
  const unsigned int w0 = p[lane];
  const unsigned int w1 = p[64 + lane];
  int cnt = 0;
  const unsigned short us[4] = {
      (unsigned short)(w0 & 0xffffu), (unsigned short)(w0 >> 16),
      (unsigned short)(w1 & 0xffffu), (unsigned short)(w1 >> 16)};
#pragma unroll
  for (int h = 0; h < 4; ++h) {
    const float a = fabsf(bf2f(us[h]));
    cnt += (a > 9.0e-13f && a < 32.0f) ? 1 : 0;
  }
#pragma unroll
  for (int mm = 32; mm >= 1; mm >>= 1) cnt += __shfl_xor(cnt, mm, 64);
  return cnt < 220;
}

// ---------------------------------------------------------------------------
// prep: canonicalize weights into ws as split hi/lo bf16; biases+gamma fp32.
// ---------------------------------------------------------------------------
__global__ __launch_bounds__(256) void prep_kernel(
    const void* wq, const void* bq, const void* wqd, const void* bqd,
    const void* wk, const void* bk, const void* wkd, const void* bkd,
    const void* wv, const void* bv, const void* gam, const void* x,
    unsigned short* __restrict__ Whi, unsigned short* __restrict__ Wlo,
    float* __restrict__ Bcat, float* __restrict__ gamF)
{
  const int fp32mode = detect_fp32_mode(x);
  const int row = blockIdx.x;                    // 0..767
  const void* src; const void* bsrc; int srow;
  if (row < 64)       { src = wq;  bsrc = bq;  srow = row; }
  else if (row < 128) { src = wqd; bsrc = bqd; srow = row - 64; }
  else if (row < 192) { src = wk;  bsrc = bk;  srow = row - 128; }
  else if (row < 256) { src = wkd; bsrc = bkd; srow = row - 192; }
  else                { src = wv;  bsrc = bv;  srow = row - 256; }
  for (int c = threadIdx.x; c < 512; c += 256) {
    const float v = fp32mode ? ((const float*)src)[(size_t)srow * 512 + c]
                             : bf2f(((const unsigned short*)src)[(size_t)srow * 512 + c]);
    const unsigned short h = f2bf(v);
    Whi[(size_t)row * 512 + c] = h;
    Wlo[(size_t)row * 512 + c] = f2bf(v - bf2f(h));
  }
  if (threadIdx.x == 0) {
    Bcat[row] = fp32mode ? ((const float*)bsrc)[srow]
                         : bf2f(((const unsigned short*)bsrc)[srow]);
    if (row == 0)
      gamF[0] = fp32mode ? ((const float*)gam)[0]
                         : bf2f(((const unsigned short*)gam)[0]);
  }
}

// ---------------------------------------------------------------------------
// Projection tile -> LDS assembly buffers (exact final layouts):
//   QT 16KB: hi[n*256 + d*2] | lo (+8192)          n = local row 0..31
//   KT 16KB: hi[(n*256 + d*2)^((n&7)<<4)] | lo (+8192)
//   VT 32KB: [(c*64 + n*2)^((c&7)<<4)]
// W fragments batch-prefetched into registers (16..32 loads in flight, one
// drain) -- kills the per-ks global-load latency chain (round-11 lesson).
// 6 independent accumulator chains for MFMA ILP.
// ---------------------------------------------------------------------------
__device__ __forceinline__ void do_tile2(
    const unsigned short* __restrict__ Whi, const unsigned short* __restrict__ Wlo,
    const float* bsh,
    const unsigned short* Xhi, const unsigned short* Xlo, int fp32mode,
    int wrow0, int kind, int d0,
    int l15, int quad,
    char* __restrict__ QT, char* __restrict__ KT, char* __restrict__ VT)
{
  // ---- batched W prefetch (static indices -> stays in VGPRs) ----
  bf16x8 wh[16], wl[16];
  {
    const unsigned short* whi = Whi + (size_t)(wrow0 + l15) * 512 + quad * 8;
#pragma unroll
    for (int ks = 0; ks < 16; ++ks)
      wh[ks] = *(const bf16x8*)(whi + ks * 32);
    if (fp32mode) {
      const unsigned short* wlo = Wlo + (size_t)(wrow0 + l15) * 512 + quad * 8;
#pragma unroll
      for (int ks = 0; ks < 16; ++ks)
        wl[ks] = *(const bf16x8*)(wlo + ks * 32);
    }
  }
  f32x4 A0, A1, B0, B1, C0, C1;
#pragma unroll
  for (int r = 0; r < 4; ++r) {
    A0[r] = A1[r] = bsh[wrow0 + quad * 4 + r];
    B0[r] = B1[r] = C0[r] = C1[r] = 0.f;
  }
  const unsigned short* x0h = Xhi + l15 * 522;
  const unsigned short* x1h = Xhi + (16 + l15) * 522;
  const unsigned short* x0l = Xlo + l15 * 522;
  const unsigned short* x1l = Xlo + (16 + l15) * 522;
#pragma unroll
  for (int ks = 0; ks < 16; ++ks) {
    const int o = ks * 32 + quad * 8;
    const bf16x8 b0 = *(const bf16x8*)(x0h + o);
    const bf16x8 b1 = *(const bf16x8*)(x1h + o);
    A0 = __builtin_amdgcn_mfma_f32_16x16x32_bf16(wh[ks], b0, A0, 0, 0, 0);
    A1 = __builtin_amdgcn_mfma_f32_16x16x32_bf16(wh[ks], b1, A1, 0, 0, 0);
    if (fp32mode) {
      const bf16x8 c0 = *(const bf16x8*)(x0l + o);
      const bf16x8 c1 = *(const bf16x8*)(x1l + o);
      B0 = __builtin_amdgcn_mfma_f32_16x16x32_bf16(wh[ks], c0, B0, 0, 0, 0);
      C0 = __builtin_amdgcn_mfma_f32_16x16x32_bf16(wl[ks], b0, C0, 0, 0, 0);
      B1 = __builtin_amdgcn_mfma_f32_16x16x32_bf16(wh[ks], c1, B1, 0, 0, 0);
      C1 = __builtin_amdgcn_mfma_f32_16x16x32_bf16(wl[ks], b1, C1, 0, 0, 0);
    }
  }
  const f32x4 a0 = fp32mode ? (A0 + B0) + C0 : A0;
  const f32x4 a1 = fp32mode ? (A1 + B1) + C1 : A1;
#pragma unroll
  for (int ns = 0; ns < 2; ++ns) {
    const f32x4 acc = ns ? a1 : a0;
    const int n = ns * 16 + l15;                 // local row
    if (kind <= 1) {                             // Q or K
      ushort4 h, l;
#pragma unroll
      for (int r = 0; r < 4; ++r) {
        const float f = acc[r];
        const unsigned short hh = f2bf(f);
        ((unsigned short*)&h)[r] = hh;
        ((unsigned short*)&l)[r] = f2bf(f - bf2f(hh));
      }
      const unsigned lin = (unsigned)(n * 256 + (d0 + quad * 4) * 2);
      if (kind == 0) {
        *(ushort4*)(QT + lin) = h;
        *(ushort4*)(QT + 8192 + lin) = l;
      } else {
        const unsigned off = lin ^ ((unsigned)(n & 7) << 4);
        *(ushort4*)(KT + off) = h;
        *(ushort4*)(KT + 8192 + off) = l;
      }
    } else {                                     // V
#pragma unroll
      for (int r = 0; r < 4; ++r) {
        const int c = d0 + quad * 4 + r;
        const unsigned off =
            ((unsigned)(c * 64 + n * 2)) ^ ((unsigned)(c & 7) << 4);
        *(unsigned short*)(VT + off) = f2bf(acc[r]);
      }
    }
  }
}

__global__ __launch_bounds__(512, 2) void proj_kernel(
    const void* __restrict__ x, const void* __restrict__ dep,
    const unsigned short* __restrict__ Whi, const unsigned short* __restrict__ Wlo,
    const float* __restrict__ Bcat,
    unsigned short* __restrict__ Qhi, unsigned short* __restrict__ Qlo,
    unsigned short* __restrict__ Kst, unsigned short* __restrict__ Vst)
{
  __shared__ unsigned short Xhi[32 * 522];   // 33.4 KB (stride 522: bank spread)
  __shared__ unsigned short Xlo[32 * 522];
  __shared__ char QT[16384];                 // Q tile: hi 8K | lo 8K
  __shared__ char KT[16384];                 // K tile: hi 8K | lo 8K (swizzled)
  __shared__ char VT[32768];                 // V tile (swizzled)
  __shared__ float bsh[768];
  const int fp32mode = detect_fp32_mode(x);
  const int tid  = threadIdx.x;
  const int lane = tid & 63;
  const int w    = tid >> 6;           // 0..7
  const int l15  = lane & 15;
  const int quad = lane >> 4;
  const int b  = blockIdx.y;
  const int t  = blockIdx.x;           // n-tile index (32 rows)
  const int n0 = t * 32;

  const int cbase = tid >> 4;          // 0..31
  const int nn    = (tid & 15) * 2;

  for (int i = tid; i < 768; i += 512) bsh[i] = Bcat[i];

  // ---- stage X (from x) ----
  for (int r = 0; r < 16; ++r) {
    const int c = cbase + r * 32;
    const size_t off = (((size_t)b * 512 + c) << 12) + n0 + nn;
    float v0, v1;
    if (fp32mode) {
      const float2 f2 = *(const float2*)((const float*)x + off);
      v0 = f2.x; v1 = f2.y;
    } else {
      const unsigned int v2 = *(const unsigned int*)((const unsigned short*)x + off);
      v0 = bflo(v2 & 0xffffu); v1 = bflo(v2 >> 16);
    }
    const unsigned short h0 = f2bf(v0), h1 = f2bf(v1);
    Xhi[nn * 522 + c]       = h0;
    Xhi[(nn + 1) * 522 + c] = h1;
    Xlo[nn * 522 + c]       = f2bf(v0 - bf2f(h0));
    Xlo[(nn + 1) * 522 + c] = f2bf(v1 - bf2f(h1));
  }
  __syncthreads();

  // ---- stage-1 (from x): 40 tiles = wq(4) | wk(4) | wv(32); wave stride 8 ----
  for (int rt = w; rt < 40; rt += 8) {
    if (rt < 4)
      do_tile2(Whi, Wlo, bsh, Xhi, Xlo, fp32mode, rt * 16,             0, rt * 16,
               l15, quad, QT, KT, VT);
    else if (rt < 8)
      do_tile2(Whi, Wlo, bsh, Xhi, Xlo, fp32mode, 128 + (rt - 4) * 16, 1, (rt - 4) * 16,
               l15, quad, QT, KT, VT);
    else
      do_tile2(Whi, Wlo, bsh, Xhi, Xlo, fp32mode, 256 + (rt - 8) * 16, 2, (rt - 8) * 16,
               l15, quad, QT, KT, VT);
  }
  __syncthreads();

  // ---- dump V (coalesced 16B), then stage X (from dep) ----
  {
    char* vdst = (char*)Vst + (((size_t)b * 128 + t) << 15);
#pragma unroll
    for (int i = 0; i < 4; ++i) {
      const int off = i * 8192 + tid * 16;
      *(uint4*)(vdst + off) = *(const uint4*)(VT + off);
    }
  }
  for (int r = 0; r < 16; ++r) {
    const int c = cbase + r * 32;
    const size_t off = (((size_t)b * 512 + c) << 12) + n0 + nn;
    float v0, v1;
    if (fp32mode) {
      const float2 f2 = *(const float2*)((const float*)dep + off);
      v0 = f2.x; v1 = f2.y;
    } else {
      const unsigned int v2 = *(const unsigned int*)((const unsigned short*)dep + off);
      v0 = bflo(v2 & 0xffffu); v1 = bflo(v2 >> 16);
    }
    const unsigned short h0 = f2bf(v0), h1 = f2bf(v1);
    Xhi[nn * 522 + c]       = h0;
    Xhi[(nn + 1) * 522 + c] = h1;
    Xlo[nn * 522 + c]       = f2bf(v0 - bf2f(h0));
    Xlo[(nn + 1) * 522 + c] = f2bf(v1 - bf2f(h1));
  }
  __syncthreads();

  // ---- stage-2 (from dep): wqd(4) | wkd(4), one tile per wave, d-base 64 ----
  {
    const int rt = w;
    if (rt < 4)
      do_tile2(Whi, Wlo, bsh, Xhi, Xlo, fp32mode, 64 + rt * 16,        0, 64 + rt * 16,
               l15, quad, QT, KT, VT);
    else
      do_tile2(Whi, Wlo, bsh, Xhi, Xlo, fp32mode, 192 + (rt - 4) * 16, 1, 64 + (rt - 4) * 16,
               l15, quad, QT, KT, VT);
  }
  __syncthreads();

  // ---- dump Q + K (coalesced 16B) ----
  {
    char* kdst = (char*)Kst + (((size_t)b * 128 + t) << 14);
#pragma unroll
    for (int i = 0; i < 2; ++i) {
      const int off = i * 8192 + tid * 16;
      *(uint4*)(kdst + off) = *(const uint4*)(KT + off);
    }
    const size_t qoff = ((((size_t)b << 12) + n0) * 128) * 2;   // bytes
    *(uint4*)((char*)Qhi + qoff + tid * 16) = *(const uint4*)(QT + tid * 16);
    *(uint4*)((char*)Qlo + qoff + tid * 16) = *(const uint4*)(QT + 8192 + tid * 16);
  }
}

// ---------------------------------------------------------------------------
// Producer/consumer flash attention (unchanged from round 10).
// Grid: 256 blocks x 768 thr (12 waves). Block = 64 rows of one batch.
// Waves 0..3: energy; waves 4..11: PV (64-ch slice owner). 1 barrier/iter,
// P[2] parity dbuf, counted vmcnt per role, setprio on MFMA clusters.
// LDS: KL 32K + VL 64K + P 10K + lstat = 106.5K -> 1 block/CU, 3 waves/SIMD.
// ---------------------------------------------------------------------------
__global__ __launch_bounds__(768, 3) void attn_kernel(
    const unsigned short* __restrict__ Qhi, const unsigned short* __restrict__ Qlo,
    const unsigned short* __restrict__ Kst, const unsigned short* __restrict__ Vst,
    const void* __restrict__ x, const float* __restrict__ gamF,
    void* __restrict__ outp)
{
  __shared__ char KL[2][16384];          // [buf][hi 8KB | lo 8KB] swizzled
  __shared__ char VL[2][32768];          // [buf][512c x 32j] swizzled
  __shared__ unsigned short P[2][64][40];// [buf][i][j] stride 80B
  __shared__ float lstat[2][4][16];      // [jt][itg][row]

  const int fp32mode = detect_fp32_mode(x);
  const int tid  = threadIdx.x;
  const int lane = tid & 63;
  const int w    = tid >> 6;          // 0..11
  const int l15  = lane & 15;
  const int quad = lane >> 4;
  const int id   = blockIdx.x;
  const int b    = (id >> 1) & 3;
  const int n0   = (((id >> 3) << 1) | (id & 1)) * 64;

  // Force fp32mode's global loads to fully retire before any gld16 below,
  // so the counted-vmcnt FIFO sees only staging loads.
  asm volatile("" :: "v"(fp32mode) : "memory");

  const char* Kb = (const char*)Kst + (((size_t)b * 128) << 14);
  const char* Vb = (const char*)Vst + (((size_t)b * 128) << 15);

  if (w < 4) {
    // =========================== ENERGY ROLE ===========================
    const int ihE = w >> 1;            // 32-row half of the 64-row block
    const int jt  = w & 1;             // 16-j half of the 32-j tile
    bf16x8 qh[2][4], ql[2][4];
#pragma unroll
    for (int itq = 0; itq < 2; ++itq) {
      const size_t qb =
          (((size_t)b << 12) + n0 + ihE * 32 + itq * 16 + l15) * 128 + quad * 8;
#pragma unroll
      for (int ds = 0; ds < 4; ++ds) {
        qh[itq][ds] = *(const bf16x8*)(Qhi + qb + ds * 32);
        ql[itq][ds] = *(const bf16x8*)(Qlo + qb + ds * 32);
      }
    }
    // prologue: stage K(0) -> KL[0] (4 chunks of 1KB)
#pragma unroll
    for (int ch = 0; ch < 4; ++ch) {
      const int c = w + ch * 4;
      gld16(Kb + c * 1024 + lane * 16, &KL[0][c * 1024]);
    }
    float lpart[2] = {0.f, 0.f};

    for (int t = 0; t <= 128; ++t) {
      asm volatile("s_waitcnt vmcnt(0) lgkmcnt(0)" ::: "memory");
      __builtin_amdgcn_sched_barrier(0);
      __builtin_amdgcn_s_barrier();
      __builtin_amdgcn_sched_barrier(0);
      if (t < 128) {
        const int cur = t & 1;
        if (t < 127) {                 // stage K(t+1) -> KL[nxt]
          const char* src = Kb + ((size_t)(t + 1) << 14);
#pragma unroll
          for (int ch = 0; ch < 4; ++ch) {
            const int c = w + ch * 4;
            gld16(src + c * 1024 + lane * 16, &KL[cur ^ 1][c * 1024]);
          }
        }
        __builtin_amdgcn_sched_barrier(0);
        const int row = jt * 16 + l15;
        const unsigned rsw = (unsigned)(row & 7) << 4;
        const char* kb = &KL[cur][0];
        bf16x8 kh[4], kl[4];
#pragma unroll
        for (int ds = 0; ds < 4; ++ds) {
          const unsigned off = ((unsigned)(row * 256 + quad * 16 + ds * 64)) ^ rsw;
          kh[ds] = *(const bf16x8*)(kb + off);
          kl[ds] = *(const bf16x8*)(kb + 8192 + off);
        }
        f32x4 ea[2], eb[2], ec[2];
#pragma unroll
        for (int itq = 0; itq < 2; ++itq) {
          ea[itq] = (f32x4){0.f, 0.f, 0.f, 0.f};
          eb[itq] = (f32x4){0.f, 0.f, 0.f, 0.f};
          ec[itq] = (f32x4){0.f, 0.f, 0.f, 0.f};
        }
        __builtin_amdgcn_s_setprio(1);
#pragma unroll
        for (int ds = 0; ds < 4; ++ds)
#pragma unroll
          for (int itq = 0; itq < 2; ++itq) {
            ea[itq] = __builtin_amdgcn_mfma_f32_16x16x32_bf16(kh[ds], qh[itq][ds], ea[itq], 0, 0, 0);
            eb[itq] = __builtin_amdgcn_mfma_f32_16x16x32_bf16(kh[ds], ql[itq][ds], eb[itq], 0, 0, 0);
            ec[itq] = __builtin_amdgcn_mfma_f32_16x16x32_bf16(kl[ds], qh[itq][ds], ec[itq], 0, 0, 0);
          }
        __builtin_amdgcn_s_setprio(0);
#pragma unroll
        for (int itq = 0; itq < 2; ++itq) {
          const f32x4 e = (ea[itq] + eb[itq]) + ec[itq];
          const float p0 = __expf(e[0] - 32.0f);
          const float p1 = __expf(e[1] - 32.0f);
          const float p2 = __expf(e[2] - 32.0f);
          const float p3 = __expf(e[3] - 32.0f);
          const unsigned short u0 = f2bf(p0), u1 = f2bf(p1);
          const unsigned short u2 = f2bf(p2), u3 = f2bf(p3);
          lpart[itq] += (bf2f(u0) + bf2f(u1)) + (bf2f(u2) + bf2f(u3));
          unsigned int* dst = (unsigned int*)
              (&P[cur][ihE * 32 + itq * 16 + l15][jt * 16 + quad * 4]);
          dst[0] = (unsigned int)u0 | ((unsigned int)u1 << 16);
          dst[1] = (unsigned int)u2 | ((unsigned int)u3 << 16);
        }
      }
    }
    // l partials -> lstat
#pragma unroll
    for (int itq = 0; itq < 2; ++itq) {
      float lp = lpart[itq];
      lp += __shfl_xor(lp, 16, 64);
      lp += __shfl_xor(lp, 32, 64);
      if (quad == 0) lstat[jt][ihE * 2 + itq][l15] = lp;
    }
    __syncthreads();
    return;
  }

  // ============================= PV ROLE ==============================
  const int wv = w - 4;                // 64-channel slice owner
#pragma unroll
  for (int k = 0; k < 4; ++k) {
    const int c = wv * 4 + k;
    gld16(Vb + c * 1024 + lane * 16, &VL[0][c * 1024]);
  }
  f32x4 acc[4][4];                     // [ct][itv] = 64 regs
#pragma unroll
  for (int ct = 0; ct < 4; ++ct)
#pragma unroll
    for (int itv = 0; itv < 4; ++itv) acc[ct][itv] = (f32x4){0.f, 0.f, 0.f, 0.f};

  for (int t = 0; t <= 128; ++t) {
    if (t <= 127)
      asm volatile("s_waitcnt vmcnt(4)" ::: "memory");
    else
      asm volatile("s_waitcnt vmcnt(0)" ::: "memory");
    __builtin_amdgcn_sched_barrier(0);
    __builtin_amdgcn_s_barrier();
    __builtin_amdgcn_sched_barrier(0);
    if (t >= 1) {
      const int pb = (t - 1) & 1;
      bf16x8 pf[4];
#pragma unroll
      for (int itv = 0; itv < 4; ++itv)
        pf[itv] = *(const bf16x8*)(&P[pb][itv * 16 + l15][quad * 8]);
      const char* vb = &VL[pb][0];
      __builtin_amdgcn_s_setprio(1);
#pragma unroll
      for (int ct = 0; ct < 4; ++ct) {
        const int c = wv * 64 + ct * 16 + l15;
        const unsigned off =
            ((unsigned)(c * 64 + quad * 16)) ^ ((unsigned)(c & 7) << 4);
        const bf16x8 va = *(const bf16x8*)(vb + off);
#pragma unroll
        for (int itv = 0; itv < 4; ++itv)
          acc[ct][itv] = __builtin_amdgcn_mfma_f32_16x16x32_bf16(va, pf[itv], acc[ct][itv], 0, 0, 0);
      }
      __builtin_amdgcn_s_setprio(0);
      __builtin_amdgcn_sched_barrier(0);
    }
    if (t < 127) {                     // stage V(t+1) own slice (post-read)
      const char* src = Vb + ((size_t)(t + 1) << 15);
#pragma unroll
      for (int k = 0; k < 4; ++k) {
        const int c = wv * 4 + k;
        gld16(src + c * 1024 + lane * 16, &VL[(t + 1) & 1][c * 1024]);
      }
    }
  }
  __syncthreads();

  // ---- epilogue: out[c][n] = gamma*O/l + x for my 64-channel slice ----
  const float gv = gamF[0];
  float sc[4];
#pragma unroll
  for (int itv = 0; itv < 4; ++itv) {
    const float l = lstat[0][itv][l15] + lstat[1][itv][l15];
    sc[itv] = gv / l;
  }
#pragma unroll
  for (int ct = 0; ct < 4; ++ct)
#pragma unroll
    for (int r = 0; r < 4; ++r) {
      const int c_g = wv * 64 + ct * 16 + quad * 4 + r;
      const size_t brow = ((size_t)b * 512 + c_g) << 12;
#pragma unroll
      for (int itv = 0; itv < 4; ++itv) {
        const size_t addr = brow + n0 + itv * 16 + l15;
        const float o = sc[itv] * acc[ct][itv][r];
        if (fp32mode) {
          ((float*)outp)[addr] = o + ((const float*)x)[addr];
        } else {
          ((unsigned short*)outp)[addr] =
              f2bf(o + bf2f(((const unsigned short*)x)[addr]));
        }
      }
    }
}

extern "C" void kernel_launch(void* const* d_in, const int* in_sizes, int n_in,
                              void* d_out, int out_size, void* d_ws, size_t ws_size,
                              hipStream_t stream) {
  const void* x    = d_in[0];
  const void* dep  = d_in[1];
  const void* wq   = d_in[2];
  const void* bq   = d_in[3];
  const void* wqd  = d_in[4];
  const void* bqd  = d_in[5];
  const void* wk   = d_in[6];
  const void* bk   = d_in[7];
  const void* wkd  = d_in[8];
  const void* bkd  = d_in[9];
  const void* wv   = d_in[10];
  const void* bv   = d_in[11];
  const void* gam  = d_in[12];

  // ws: Whi(768K) Wlo(768K) Bcat gamF | @2M Qhi 4M | @6M Qlo 4M
  //     | @10M Kst 8M (tiled+swizzled) | @18M Vst 16M (tiled+swizzled)
  unsigned short* Whi = (unsigned short*)d_ws;
  unsigned short* Wlo = Whi + (size_t)768 * 512;
  float* Bcat = (float*)(Wlo + (size_t)768 * 512);
  float* gamF = Bcat + 768;
  unsigned short* Qhi = (unsigned short*)((char*)d_ws + ((size_t)2 << 20));
  unsigned short* Qlo = (unsigned short*)((char*)d_ws + ((size_t)6 << 20));
  unsigned short* Kst = (unsigned short*)((char*)d_ws + ((size_t)10 << 20));
  unsigned short* Vst = (unsigned short*)((char*)d_ws + ((size_t)18 << 20));

  prep_kernel<<<768, 256, 0, stream>>>(wq, bq, wqd, bqd, wk, bk, wkd, bkd,
                                       wv, bv, gam, x, Whi, Wlo, Bcat, gamF);
  proj_kernel<<<dim3(128, 4), 512, 0, stream>>>(x, dep, Whi, Wlo, Bcat,
                                                Qhi, Qlo, Kst, Vst);
  attn_kernel<<<256, 768, 0, stream>>>(Qhi, Qlo, Kst, Vst, x, gamF, d_out);
}

// Round 8
// 442.392 us; speedup vs baseline: 1.0623x; 1.0623x over previous
//
#include <hip/hip_runtime.h>

// ---------------------------------------------------------------------------
// PAM_Module_Dep: dual-modality position attention. B=4, C=512, N=4096, CQ=64.
// Round 13: proj staging-load batching (attn unchanged from round 10).
//   Rounds 10-12 evidence: three structurally different proj kernels all at
//   229-240us. Store fix landed (WRITE clean), occupancy 3.4x landed, W-batch
//   landed (VGPR 128) -- duration invariant. Remaining invariant: x/dep
//   staging loop load->convert->LDS-write keeps ~1 load in flight per wave;
//   8 waves/CU x 128B = 1KB outstanding/CU -> ~400GB/s chip cap == measured
//   360-380 GB/s. proj is issue-serialized on its compulsory 64MB read.
// Fix: per staging pass, issue all 16 loads into static-index reg arrays
//   FIRST, then convert+write LDS (progressive vmcnt drains). 16 in flight
//   per wave -> staging becomes HBM-limited (~10us chip-wide).
// proj otherwise as r12: LDS tile assembly in exact swizzled layouts,
//   coalesced uint4 dumps, batched W prefetch, 6 acc chains, stride-522.
// attn: producer/consumer wave specialization (r10): 4 energy waves + 8 PV
//   waves, 1 barrier/iter, counted vmcnt, P parity dbuf. Math retained:
//   constant mhat=32, split-bf16 exact energy (hh+hl+lh), p rounded to bf16
//   with l summed from rounded p, O^T=V^T*P^T, out = gamma*O/l + x.
// ---------------------------------------------------------------------------

typedef __attribute__((ext_vector_type(8))) short bf16x8;
typedef __attribute__((ext_vector_type(4))) float f32x4;

__device__ __forceinline__ float bf2f(unsigned short u) {
  return __builtin_bit_cast(float, (unsigned int)u << 16);
}
__device__ __forceinline__ unsigned short f2bf(float f) {
  unsigned int u = __builtin_bit_cast(unsigned int, f);
  u = u + 0x7fffu + ((u >> 16) & 1u);   // RNE
  return (unsigned short)(u >> 16);
}
__device__ __forceinline__ float bflo(unsigned int u) {
  return __builtin_bit_cast(float, u << 16);
}

// Async 16B/lane global->LDS DMA (wave writes ldsbase + lane*16).
__device__ __forceinline__ void gld16(const char* g, char* l) {
  __builtin_amdgcn_global_load_lds(
      (const __attribute__((address_space(1))) unsigned int*)g,
      (__attribute__((address_space(3))) unsigned int*)l, 16, 0, 0);
}

// Returns 1 if x looks like fp32 data, 0 if bf16. Wave-uniform, deterministic.
__device__ __forceinline__ int detect_fp32_mode(const void* xv) {
  const unsigned int* p = (const unsigned int*)xv;
  const int lane = threadIdx.x & 63;
  const unsigned int w0 = p[lane];
  const unsigned int w1 = p[64 + lane];
  int cnt = 0;
  const unsigned short us[4] = {
      (unsigned short)(w0 & 0xffffu), (unsigned short)(w0 >> 16),
      (unsigned short)(w1 & 0xffffu), (unsigned short)(w1 >> 16)};
#pragma unroll
  for (int h = 0; h < 4; ++h) {
    const float a = fabsf(bf2f(us[h]));
    cnt += (a > 9.0e-13f && a < 32.0f) ? 1 : 0;
  }
#pragma unroll
  for (int mm = 32; mm >= 1; mm >>= 1) cnt += __shfl_xor(cnt, mm, 64);
  return cnt < 220;
}

// ---------------------------------------------------------------------------
// prep: canonicalize weights into ws as split hi/lo bf16; biases+gamma fp32.
// ---------------------------------------------------------------------------
__global__ __launch_bounds__(256) void prep_kernel(
    const void* wq, const void* bq, const void* wqd, const void* bqd,
    const void* wk, const void* bk, const void* wkd, const void* bkd,
    const void* wv, const void* bv, const void* gam, const void* x,
    unsigned short* __restrict__ Whi, unsigned short* __restrict__ Wlo,
    float* __restrict__ Bcat, float* __restrict__ gamF)
{
  const int fp32mode = detect_fp32_mode(x);
  const int row = blockIdx.x;                    // 0..767
  const void* src; const void* bsrc; int srow;
  if (row < 64)       { src = wq;  bsrc = bq;  srow = row; }
  else if (row < 128) { src = wqd; bsrc = bqd; srow = row - 64; }
  else if (row < 192) { src = wk;  bsrc = bk;  srow = row - 128; }
  else if (row < 256) { src = wkd; bsrc = bkd; srow = row - 192; }
  else                { src = wv;  bsrc = bv;  srow = row - 256; }
  for (int c = threadIdx.x; c < 512; c += 256) {
    const float v = fp32mode ? ((const float*)src)[(size_t)srow * 512 + c]
                             : bf2f(((const unsigned short*)src)[(size_t)srow * 512 + c]);
    const unsigned short h = f2bf(v);
    Whi[(size_t)row * 512 + c] = h;
    Wlo[(size_t)row * 512 + c] = f2bf(v - bf2f(h));
  }
  if (threadIdx.x == 0) {
    Bcat[row] = fp32mode ? ((const float*)bsrc)[srow]
                         : bf2f(((const unsigned short*)bsrc)[srow]);
    if (row == 0)
      gamF[0] = fp32mode ? ((const float*)gam)[0]
                         : bf2f(((const unsigned short*)gam)[0]);
  }
}

// ---------------------------------------------------------------------------
// Batched X staging: 16 independent loads issued into static-index register
// arrays FIRST (16 in flight), then convert + LDS write (progressive drains).
// This is the round-13 fix for the ~400GB/s issue-serialization cap.
// ---------------------------------------------------------------------------
__device__ __forceinline__ void stage_X(
    const void* __restrict__ src, int fp32mode, int b, int n0,
    int cbase, int nn,
    unsigned short* __restrict__ Xhi, unsigned short* __restrict__ Xlo)
{
  float v0a[16], v1a[16];
  if (fp32mode) {
    const float* s = (const float*)src;
#pragma unroll
    for (int r = 0; r < 16; ++r) {
      const int c = cbase + r * 32;
      const float2 f2 = *(const float2*)(s + (((size_t)b * 512 + c) << 12) + n0 + nn);
      v0a[r] = f2.x; v1a[r] = f2.y;
    }
  } else {
    const unsigned short* s = (const unsigned short*)src;
#pragma unroll
    for (int r = 0; r < 16; ++r) {
      const int c = cbase + r * 32;
      const unsigned int v2 =
          *(const unsigned int*)(s + (((size_t)b * 512 + c) << 12) + n0 + nn);
      v0a[r] = bflo(v2 & 0xffffu); v1a[r] = bflo(v2 >> 16);
    }
  }
#pragma unroll
  for (int r = 0; r < 16; ++r) {
    const int c = cbase + r * 32;
    const unsigned short h0 = f2bf(v0a[r]), h1 = f2bf(v1a[r]);
    Xhi[nn * 522 + c]       = h0;
    Xhi[(nn + 1) * 522 + c] = h1;
    Xlo[nn * 522 + c]       = f2bf(v0a[r] - bf2f(h0));
    Xlo[(nn + 1) * 522 + c] = f2bf(v1a[r] - bf2f(h1));
  }
}

// ---------------------------------------------------------------------------
// Projection tile -> LDS assembly buffers (exact final layouts):
//   QT 16KB: hi[n*256 + d*2] | lo (+8192)          n = local row 0..31
//   KT 16KB: hi[(n*256 + d*2)^((n&7)<<4)] | lo (+8192)
//   VT 32KB: [(c*64 + n*2)^((c&7)<<4)]
// W fragments batch-prefetched into registers; 6 independent acc chains.
// ---------------------------------------------------------------------------
__device__ __forceinline__ void do_tile2(
    const unsigned short* __restrict__ Whi, const unsigned short* __restrict__ Wlo,
    const float* bsh,
    const unsigned short* Xhi, const unsigned short* Xlo, int fp32mode,
    int wrow0, int kind, int d0,
    int l15, int quad,
    char* __restrict__ QT, char* __restrict__ KT, char* __restrict__ VT)
{
  // ---- batched W prefetch (static indices -> stays in VGPRs) ----
  bf16x8 wh[16], wl[16];
  {
    const unsigned short* whi = Whi + (size_t)(wrow0 + l15) * 512 + quad * 8;
#pragma unroll
    for (int ks = 0; ks < 16; ++ks)
      wh[ks] = *(const bf16x8*)(whi + ks * 32);
    if (fp32mode) {
      const unsigned short* wlo = Wlo + (size_t)(wrow0 + l15) * 512 + quad * 8;
#pragma unroll
      for (int ks = 0; ks < 16; ++ks)
        wl[ks] = *(const bf16x8*)(wlo + ks * 32);
    }
  }
  f32x4 A0, A1, B0, B1, C0, C1;
#pragma unroll
  for (int r = 0; r < 4; ++r) {
    A0[r] = A1[r] = bsh[wrow0 + quad * 4 + r];
    B0[r] = B1[r] = C0[r] = C1[r] = 0.f;
  }
  const unsigned short* x0h = Xhi + l15 * 522;
  const unsigned short* x1h = Xhi + (16 + l15) * 522;
  const unsigned short* x0l = Xlo + l15 * 522;
  const unsigned short* x1l = Xlo + (16 + l15) * 522;
#pragma unroll
  for (int ks = 0; ks < 16; ++ks) {
    const int o = ks * 32 + quad * 8;
    const bf16x8 b0 = *(const bf16x8*)(x0h + o);
    const bf16x8 b1 = *(const bf16x8*)(x1h + o);
    A0 = __builtin_amdgcn_mfma_f32_16x16x32_bf16(wh[ks], b0, A0, 0, 0, 0);
    A1 = __builtin_amdgcn_mfma_f32_16x16x32_bf16(wh[ks], b1, A1, 0, 0, 0);
    if (fp32mode) {
      const bf16x8 c0 = *(const bf16x8*)(x0l + o);
      const bf16x8 c1 = *(const bf16x8*)(x1l + o);
      B0 = __builtin_amdgcn_mfma_f32_16x16x32_bf16(wh[ks], c0, B0, 0, 0, 0);
      C0 = __builtin_amdgcn_mfma_f32_16x16x32_bf16(wl[ks], b0, C0, 0, 0, 0);
      B1 = __builtin_amdgcn_mfma_f32_16x16x32_bf16(wh[ks], c1, B1, 0, 0, 0);
      C1 = __builtin_amdgcn_mfma_f32_16x16x32_bf16(wl[ks], b1, C1, 0, 0, 0);
    }
  }
  const f32x4 a0 = fp32mode ? (A0 + B0) + C0 : A0;
  const f32x4 a1 = fp32mode ? (A1 + B1) + C1 : A1;
#pragma unroll
  for (int ns = 0; ns < 2; ++ns) {
    const f32x4 acc = ns ? a1 : a0;
    const int n = ns * 16 + l15;                 // local row
    if (kind <= 1) {                             // Q or K
      ushort4 h, l;
#pragma unroll
      for (int r = 0; r < 4; ++r) {
        const float f = acc[r];
        const unsigned short hh = f2bf(f);
        ((unsigned short*)&h)[r] = hh;
        ((unsigned short*)&l)[r] = f2bf(f - bf2f(hh));
      }
      const unsigned lin = (unsigned)(n * 256 + (d0 + quad * 4) * 2);
      if (kind == 0) {
        *(ushort4*)(QT + lin) = h;
        *(ushort4*)(QT + 8192 + lin) = l;
      } else {
        const unsigned off = lin ^ ((unsigned)(n & 7) << 4);
        *(ushort4*)(KT + off) = h;
        *(ushort4*)(KT + 8192 + off) = l;
      }
    } else {                                     // V
#pragma unroll
      for (int r = 0; r < 4; ++r) {
        const int c = d0 + quad * 4 + r;
        const unsigned off =
            ((unsigned)(c * 64 + n * 2)) ^ ((unsigned)(c & 7) << 4);
        *(unsigned short*)(VT + off) = f2bf(acc[r]);
      }
    }
  }
}

__global__ __launch_bounds__(512, 2) void proj_kernel(
    const void* __restrict__ x, const void* __restrict__ dep,
    const unsigned short* __restrict__ Whi, const unsigned short* __restrict__ Wlo,
    const float* __restrict__ Bcat,
    unsigned short* __restrict__ Qhi, unsigned short* __restrict__ Qlo,
    unsigned short* __restrict__ Kst, unsigned short* __restrict__ Vst)
{
  __shared__ unsigned short Xhi[32 * 522];   // 33.4 KB (stride 522: bank spread)
  __shared__ unsigned short Xlo[32 * 522];
  __shared__ char QT[16384];                 // Q tile: hi 8K | lo 8K
  __shared__ char KT[16384];                 // K tile: hi 8K | lo 8K (swizzled)
  __shared__ char VT[32768];                 // V tile (swizzled)
  __shared__ float bsh[768];
  const int fp32mode = detect_fp32_mode(x);
  const int tid  = threadIdx.x;
  const int lane = tid & 63;
  const int w    = tid >> 6;           // 0..7
  const int l15  = lane & 15;
  const int quad = lane >> 4;
  const int b  = blockIdx.y;
  const int t  = blockIdx.x;           // n-tile index (32 rows)
  const int n0 = t * 32;

  const int cbase = tid >> 4;          // 0..31
  const int nn    = (tid & 15) * 2;

  for (int i = tid; i < 768; i += 512) bsh[i] = Bcat[i];

  // ---- stage X (from x), batched loads ----
  stage_X(x, fp32mode, b, n0, cbase, nn, Xhi, Xlo);
  __syncthreads();

  // ---- stage-1 (from x): 40 tiles = wq(4) | wk(4) | wv(32); wave stride 8 ----
  for (int rt = w; rt < 40; rt += 8) {
    if (rt < 4)
      do_tile2(Whi, Wlo, bsh, Xhi, Xlo, fp32mode, rt * 16,             0, rt * 16,
               l15, quad, QT, KT, VT);
    else if (rt < 8)
      do_tile2(Whi, Wlo, bsh, Xhi, Xlo, fp32mode, 128 + (rt - 4) * 16, 1, (rt - 4) * 16,
               l15, quad, QT, KT, VT);
    else
      do_tile2(Whi, Wlo, bsh, Xhi, Xlo, fp32mode, 256 + (rt - 8) * 16, 2, (rt - 8) * 16,
               l15, quad, QT, KT, VT);
  }
  __syncthreads();

  // ---- dump V (coalesced 16B), then stage X (from dep), batched ----
  {
    char* vdst = (char*)Vst + (((size_t)b * 128 + t) << 15);
#pragma unroll
    for (int i = 0; i < 4; ++i) {
      const int off = i * 8192 + tid * 16;
      *(uint4*)(vdst + off) = *(const uint4*)(VT + off);
    }
  }
  stage_X(dep, fp32mode, b, n0, cbase, nn, Xhi, Xlo);
  __syncthreads();

  // ---- stage-2 (from dep): wqd(4) | wkd(4), one tile per wave, d-base 64 ----
  {
    const int rt = w;
    if (rt < 4)
      do_tile2(Whi, Wlo, bsh, Xhi, Xlo, fp32mode, 64 + rt * 16,        0, 64 + rt * 16,
               l15, quad, QT, KT, VT);
    else
      do_tile2(Whi, Wlo, bsh, Xhi, Xlo, fp32mode, 192 + (rt - 4) * 16, 1, 64 + (rt - 4) * 16,
               l15, quad, QT, KT, VT);
  }
  __syncthreads();

  // ---- dump Q + K (coalesced 16B) ----
  {
    char* kdst = (char*)Kst + (((size_t)b * 128 + t) << 14);
#pragma unroll
    for (int i = 0; i < 2; ++i) {
      const int off = i * 8192 + tid * 16;
      *(uint4*)(kdst + off) = *(const uint4*)(KT + off);
    }
    const size_t qoff = ((((size_t)b << 12) + n0) * 128) * 2;   // bytes
    *(uint4*)((char*)Qhi + qoff + tid * 16) = *(const uint4*)(QT + tid * 16);
    *(uint4*)((char*)Qlo + qoff + tid * 16) = *(const uint4*)(QT + 8192 + tid * 16);
  }
}

// ---------------------------------------------------------------------------
// Producer/consumer flash attention (unchanged from round 10).
// Grid: 256 blocks x 768 thr (12 waves). Block = 64 rows of one batch.
// Waves 0..3: energy; waves 4..11: PV (64-ch slice owner). 1 barrier/iter,
// P[2] parity dbuf, counted vmcnt per role, setprio on MFMA clusters.
// LDS: KL 32K + VL 64K + P 10K + lstat = 106.5K -> 1 block/CU, 3 waves/SIMD.
// ---------------------------------------------------------------------------
__global__ __launch_bounds__(768, 3) void attn_kernel(
    const unsigned short* __restrict__ Qhi, const unsigned short* __restrict__ Qlo,
    const unsigned short* __restrict__ Kst, const unsigned short* __restrict__ Vst,
    const void* __restrict__ x, const float* __restrict__ gamF,
    void* __restrict__ outp)
{
  __shared__ char KL[2][16384];          // [buf][hi 8KB | lo 8KB] swizzled
  __shared__ char VL[2][32768];          // [buf][512c x 32j] swizzled
  __shared__ unsigned short P[2][64][40];// [buf][i][j] stride 80B
  __shared__ float lstat[2][4][16];      // [jt][itg][row]

  const int fp32mode = detect_fp32_mode(x);
  const int tid  = threadIdx.x;
  const int lane = tid & 63;
  const int w    = tid >> 6;          // 0..11
  const int l15  = lane & 15;
  const int quad = lane >> 4;
  const int id   = blockIdx.x;
  const int b    = (id >> 1) & 3;
  const int n0   = (((id >> 3) << 1) | (id & 1)) * 64;

  // Force fp32mode's global loads to fully retire before any gld16 below,
  // so the counted-vmcnt FIFO sees only staging loads.
  asm volatile("" :: "v"(fp32mode) : "memory");

  const char* Kb = (const char*)Kst + (((size_t)b * 128) << 14);
  const char* Vb = (const char*)Vst + (((size_t)b * 128) << 15);

  if (w < 4) {
    // =========================== ENERGY ROLE ===========================
    const int ihE = w >> 1;            // 32-row half of the 64-row block
    const int jt  = w & 1;             // 16-j half of the 32-j tile
    bf16x8 qh[2][4], ql[2][4];
#pragma unroll
    for (int itq = 0; itq < 2; ++itq) {
      const size_t qb =
          (((size_t)b << 12) + n0 + ihE * 32 + itq * 16 + l15) * 128 + quad * 8;
#pragma unroll
      for (int ds = 0; ds < 4; ++ds) {
        qh[itq][ds] = *(const bf16x8*)(Qhi + qb + ds * 32);
        ql[itq][ds] = *(const bf16x8*)(Qlo + qb + ds * 32);
      }
    }
    // prologue: stage K(0) -> KL[0] (4 chunks of 1KB)
#pragma unroll
    for (int ch = 0; ch < 4; ++ch) {
      const int c = w + ch * 4;
      gld16(Kb + c * 1024 + lane * 16, &KL[0][c * 1024]);
    }
    float lpart[2] = {0.f, 0.f};

    for (int t = 0; t <= 128; ++t) {
      asm volatile("s_waitcnt vmcnt(0) lgkmcnt(0)" ::: "memory");
      __builtin_amdgcn_sched_barrier(0);
      __builtin_amdgcn_s_barrier();
      __builtin_amdgcn_sched_barrier(0);
      if (t < 128) {
        const int cur = t & 1;
        if (t < 127) {                 // stage K(t+1) -> KL[nxt]
          const char* src = Kb + ((size_t)(t + 1) << 14);
#pragma unroll
          for (int ch = 0; ch < 4; ++ch) {
            const int c = w + ch * 4;
            gld16(src + c * 1024 + lane * 16, &KL[cur ^ 1][c * 1024]);
          }
        }
        __builtin_amdgcn_sched_barrier(0);
        const int row = jt * 16 + l15;
        const unsigned rsw = (unsigned)(row & 7) << 4;
        const char* kb = &KL[cur][0];
        bf16x8 kh[4], kl[4];
#pragma unroll
        for (int ds = 0; ds < 4; ++ds) {
          const unsigned off = ((unsigned)(row * 256 + quad * 16 + ds * 64)) ^ rsw;
          kh[ds] = *(const bf16x8*)(kb + off);
          kl[ds] = *(const bf16x8*)(kb + 8192 + off);
        }
        f32x4 ea[2], eb[2], ec[2];
#pragma unroll
        for (int itq = 0; itq < 2; ++itq) {
          ea[itq] = (f32x4){0.f, 0.f, 0.f, 0.f};
          eb[itq] = (f32x4){0.f, 0.f, 0.f, 0.f};
          ec[itq] = (f32x4){0.f, 0.f, 0.f, 0.f};
        }
        __builtin_amdgcn_s_setprio(1);
#pragma unroll
        for (int ds = 0; ds < 4; ++ds)
#pragma unroll
          for (int itq = 0; itq < 2; ++itq) {
            ea[itq] = __builtin_amdgcn_mfma_f32_16x16x32_bf16(kh[ds], qh[itq][ds], ea[itq], 0, 0, 0);
            eb[itq] = __builtin_amdgcn_mfma_f32_16x16x32_bf16(kh[ds], ql[itq][ds], eb[itq], 0, 0, 0);
            ec[itq] = __builtin_amdgcn_mfma_f32_16x16x32_bf16(kl[ds], qh[itq][ds], ec[itq], 0, 0, 0);
          }
        __builtin_amdgcn_s_setprio(0);
#pragma unroll
        for (int itq = 0; itq < 2; ++itq) {
          const f32x4 e = (ea[itq] + eb[itq]) + ec[itq];
          const float p0 = __expf(e[0] - 32.0f);
          const float p1 = __expf(e[1] - 32.0f);
          const float p2 = __expf(e[2] - 32.0f);
          const float p3 = __expf(e[3] - 32.0f);
          const unsigned short u0 = f2bf(p0), u1 = f2bf(p1);
          const unsigned short u2 = f2bf(p2), u3 = f2bf(p3);
          lpart[itq] += (bf2f(u0) + bf2f(u1)) + (bf2f(u2) + bf2f(u3));
          unsigned int* dst = (unsigned int*)
              (&P[cur][ihE * 32 + itq * 16 + l15][jt * 16 + quad * 4]);
          dst[0] = (unsigned int)u0 | ((unsigned int)u1 << 16);
          dst[1] = (unsigned int)u2 | ((unsigned int)u3 << 16);
        }
      }
    }
    // l partials -> lstat
#pragma unroll
    for (int itq = 0; itq < 2; ++itq) {
      float lp = lpart[itq];
      lp += __shfl_xor(lp, 16, 64);
      lp += __shfl_xor(lp, 32, 64);
      if (quad == 0) lstat[jt][ihE * 2 + itq][l15] = lp;
    }
    __syncthreads();
    return;
  }

  // ============================= PV ROLE ==============================
  const int wv = w - 4;                // 64-channel slice owner
#pragma unroll
  for (int k = 0; k < 4; ++k) {
    const int c = wv * 4 + k;
    gld16(Vb + c * 1024 + lane * 16, &VL[0][c * 1024]);
  }
  f32x4 acc[4][4];                     // [ct][itv] = 64 regs
#pragma unroll
  for (int ct = 0; ct < 4; ++ct)
#pragma unroll
    for (int itv = 0; itv < 4; ++itv) acc[ct][itv] = (f32x4){0.f, 0.f, 0.f, 0.f};

  for (int t = 0; t <= 128; ++t) {
    if (t <= 127)
      asm volatile("s_waitcnt vmcnt(4)" ::: "memory");
    else
      asm volatile("s_waitcnt vmcnt(0)" ::: "memory");
    __builtin_amdgcn_sched_barrier(0);
    __builtin_amdgcn_s_barrier();
    __builtin_amdgcn_sched_barrier(0);
    if (t >= 1) {
      const int pb = (t - 1) & 1;
      bf16x8 pf[4];
#pragma unroll
      for (int itv = 0; itv < 4; ++itv)
        pf[itv] = *(const bf16x8*)(&P[pb][itv * 16 + l15][quad * 8]);
      const char* vb = &VL[pb][0];
      __builtin_amdgcn_s_setprio(1);
#pragma unroll
      for (int ct = 0; ct < 4; ++ct) {
        const int c = wv * 64 + ct * 16 + l15;
        const unsigned off =
            ((unsigned)(c * 64 + quad * 16)) ^ ((unsigned)(c & 7) << 4);
        const bf16x8 va = *(const bf16x8*)(vb + off);
#pragma unroll
        for (int itv = 0; itv < 4; ++itv)
          acc[ct][itv] = __builtin_amdgcn_mfma_f32_16x16x32_bf16(va, pf[itv], acc[ct][itv], 0, 0, 0);
      }
      __builtin_amdgcn_s_setprio(0);
      __builtin_amdgcn_sched_barrier(0);
    }
    if (t < 127) {                     // stage V(t+1) own slice (post-read)
      const char* src = Vb + ((size_t)(t + 1) << 15);
#pragma unroll
      for (int k = 0; k < 4; ++k) {
        const int c = wv * 4 + k;
        gld16(src + c * 1024 + lane * 16, &VL[(t + 1) & 1][c * 1024]);
      }
    }
  }
  __syncthreads();

  // ---- epilogue: out[c][n] = gamma*O/l + x for my 64-channel slice ----
  const float gv = gamF[0];
  float sc[4];
#pragma unroll
  for (int itv = 0; itv < 4; ++itv) {
    const float l = lstat[0][itv][l15] + lstat[1][itv][l15];
    sc[itv] = gv / l;
  }
#pragma unroll
  for (int ct = 0; ct < 4; ++ct)
#pragma unroll
    for (int r = 0; r < 4; ++r) {
      const int c_g = wv * 64 + ct * 16 + quad * 4 + r;
      const size_t brow = ((size_t)b * 512 + c_g) << 12;
#pragma unroll
      for (int itv = 0; itv < 4; ++itv) {
        const size_t addr = brow + n0 + itv * 16 + l15;
        const float o = sc[itv] * acc[ct][itv][r];
        if (fp32mode) {
          ((float*)outp)[addr] = o + ((const float*)x)[addr];
        } else {
          ((unsigned short*)outp)[addr] =
              f2bf(o + bf2f(((const unsigned short*)x)[addr]));
        }
      }
    }
}

extern "C" void kernel_launch(void* const* d_in, const int* in_sizes, int n_in,
                              void* d_out, int out_size, void* d_ws, size_t ws_size,
                              hipStream_t stream) {
  const void* x    = d_in[0];
  const void* dep  = d_in[1];
  const void* wq   = d_in[2];
  const void* bq   = d_in[3];
  const void* wqd  = d_in[4];
  const void* bqd  = d_in[5];
  const void* wk   = d_in[6];
  const void* bk   = d_in[7];
  const void* wkd  = d_in[8];
  const void* bkd  = d_in[9];
  const void* wv   = d_in[10];
  const void* bv   = d_in[11];
  const void* gam  = d_in[12];

  // ws: Whi(768K) Wlo(768K) Bcat gamF | @2M Qhi 4M | @6M Qlo 4M
  //     | @10M Kst 8M (tiled+swizzled) | @18M Vst 16M (tiled+swizzled)
  unsigned short* Whi = (unsigned short*)d_ws;
  unsigned short* Wlo = Whi + (size_t)768 * 512;
  float* Bcat = (float*)(Wlo + (size_t)768 * 512);
  float* gamF = Bcat + 768;
  unsigned short* Qhi = (unsigned short*)((char*)d_ws + ((size_t)2 << 20));
  unsigned short* Qlo = (unsigned short*)((char*)d_ws + ((size_t)6 << 20));
  unsigned short* Kst = (unsigned short*)((char*)d_ws + ((size_t)10 << 20));
  unsigned short* Vst = (unsigned short*)((char*)d_ws + ((size_t)18 << 20));

  prep_kernel<<<768, 256, 0, stream>>>(wq, bq, wqd, bqd, wk, bk, wkd, bkd,
                                       wv, bv, gam, x, Whi, Wlo, Bcat, gamF);
  proj_kernel<<<dim3(128, 4), 512, 0, stream>>>(x, dep, Whi, Wlo, Bcat,
                                                Qhi, Qlo, Kst, Vst);
  attn_kernel<<<256, 768, 0, stream>>>(Qhi, Qlo, Kst, Vst, x, gamF, d_out);
}

// Round 9
// 436.270 us; speedup vs baseline: 1.0772x; 1.0140x over previous
//
#include <hip/hip_runtime.h>

// ---------------------------------------------------------------------------
// PAM_Module_Dep: dual-modality position attention. B=4, C=512, N=4096, CQ=64.
// Round 14: asm-fenced batched loads in proj (attn unchanged from round 10).
//   Round-13 evidence: VGPR DROPPED 128->108 (compiler re-fused the unfenced
//   batch); proj moves 80MB at 380 GB/s = 168us ~= its duration -> the x/dep
//   staging serialization IS the wall (since r10); W-chain hid under it.
// Fix (attn's proven discipline applied to proj):
//   1. stage_X: 8x float4 loads -> static reg arrays, sched_barrier(0) fence,
//      THEN convert+LDS-write. 128B/thread in flight -> HBM-limited (~10us).
//   2. do_tile2: W in 4-ks chunks, 2-deep rolling regs (h0/l0,h1/l1),
//      explicit s_waitcnt vmcnt(8|4) + sched_barrier(0) between issue and
//      consume (only W loads outstanding in compute phase; phase boundaries
//      drain via __syncthreads).
// proj otherwise as r13: LDS tile assembly in exact swizzled layouts,
//   coalesced uint4 dumps, 6 acc chains, stride-522.
// attn: producer/consumer wave specialization (r10): 4 energy waves + 8 PV
//   waves, 1 barrier/iter, counted vmcnt, P parity dbuf. Math retained:
//   constant mhat=32, split-bf16 exact energy (hh+hl+lh), p rounded to bf16
//   with l summed from rounded p, O^T=V^T*P^T, out = gamma*O/l + x.
// ---------------------------------------------------------------------------

typedef __attribute__((ext_vector_type(8))) short bf16x8;
typedef __attribute__((ext_vector_type(4))) float f32x4;

__device__ __forceinline__ float bf2f(unsigned short u) {
  return __builtin_bit_cast(float, (unsigned int)u << 16);
}
__device__ __forceinline__ unsigned short f2bf(float f) {
  unsigned int u = __builtin_bit_cast(unsigned int, f);
  u = u + 0x7fffu + ((u >> 16) & 1u);   // RNE
  return (unsigned short)(u >> 16);
}
__device__ __forceinline__ float bflo(unsigned int u) {
  return __builtin_bit_cast(float, u << 16);
}

// Async 16B/lane global->LDS DMA (wave writes ldsbase + lane*16).
__device__ __forceinline__ void gld16(const char* g, char* l) {
  __builtin_amdgcn_global_load_lds(
      (const __attribute__((address_space(1))) unsigned int*)g,
      (__attribute__((address_space(3))) unsigned int*)l, 16, 0, 0);
}

// Returns 1 if x looks like fp32 data, 0 if bf16. Wave-uniform, deterministic.
__device__ __forceinline__ int detect_fp32_mode(const void* xv) {
  const unsigned int* p = (const unsigned int*)xv;
  const int lane = threadIdx.x & 63;
  const unsigned int w0 = p[lane];
  const unsigned int w1 = p[64 + lane];
  int cnt = 0;
  const unsigned short us[4] = {
      (unsigned short)(w0 & 0xffffu), (unsigned short)(w0 >> 16),
      (unsigned short)(w1 & 0xffffu), (unsigned short)(w1 >> 16)};
#pragma unroll
  for (int h = 0; h < 4; ++h) {
    const float a = fabsf(bf2f(us[h]));
    cnt += (a > 9.0e-13f && a < 32.0f) ? 1 : 0;
  }
#pragma unroll
  for (int mm = 32; mm >= 1; mm >>= 1) cnt += __shfl_xor(cnt, mm, 64);
  return cnt < 220;
}

// ---------------------------------------------------------------------------
// prep: canonicalize weights into ws as split hi/lo bf16; biases+gamma fp32.
// ---------------------------------------------------------------------------
__global__ __launch_bounds__(256) void prep_kernel(
    const void* wq, const void* bq, const void* wqd, const void* bqd,
    const void* wk, const void* bk, const void* wkd, const void* bkd,
    const void* wv, const void* bv, const void* gam, const void* x,
    unsigned short* __restrict__ Whi, unsigned short* __restrict__ Wlo,
    float* __restrict__ Bcat, float* __restrict__ gamF)
{
  const int fp32mode = detect_fp32_mode(x);
  const int row = blockIdx.x;                    // 0..767
  const void* src; const void* bsrc; int srow;
  if (row < 64)       { src = wq;  bsrc = bq;  srow = row; }
  else if (row < 128) { src = wqd; bsrc = bqd; srow = row - 64; }
  else if (row < 192) { src = wk;  bsrc = bk;  srow = row - 128; }
  else if (row < 256) { src = wkd; bsrc = bkd; srow = row - 192; }
  else                { src = wv;  bsrc = bv;  srow = row - 256; }
  for (int c = threadIdx.x; c < 512; c += 256) {
    const float v = fp32mode ? ((const float*)src)[(size_t)srow * 512 + c]
                             : bf2f(((const unsigned short*)src)[(size_t)srow * 512 + c]);
    const unsigned short h = f2bf(v);
    Whi[(size_t)row * 512 + c] = h;
    Wlo[(size_t)row * 512 + c] = f2bf(v - bf2f(h));
  }
  if (threadIdx.x == 0) {
    Bcat[row] = fp32mode ? ((const float*)bsrc)[srow]
                         : bf2f(((const unsigned short*)bsrc)[srow]);
    if (row == 0)
      gamF[0] = fp32mode ? ((const float*)gam)[0]
                         : bf2f(((const unsigned short*)gam)[0]);
  }
}

// ---------------------------------------------------------------------------
// Batched X staging, FENCED: issue 8 float4/uint2 loads into static reg
// arrays, sched_barrier(0) so the compiler cannot re-fuse load->use, then
// convert + LDS-write. cbase = tid>>3 (0..63), nn = (tid&7)*4.
// ---------------------------------------------------------------------------
__device__ __forceinline__ void stage_X(
    const void* __restrict__ src, int fp32mode, int b, int n0,
    int cbase, int nn,
    unsigned short* __restrict__ Xhi, unsigned short* __restrict__ Xlo)
{
  float v[8][4];
  if (fp32mode) {
    const float* s = (const float*)src;
#pragma unroll
    for (int r = 0; r < 8; ++r) {
      const int c = cbase + r * 64;
      const float4 f4 = *(const float4*)(s + (((size_t)b * 512 + c) << 12) + n0 + nn);
      v[r][0] = f4.x; v[r][1] = f4.y; v[r][2] = f4.z; v[r][3] = f4.w;
    }
  } else {
    const unsigned short* s = (const unsigned short*)src;
#pragma unroll
    for (int r = 0; r < 8; ++r) {
      const int c = cbase + r * 64;
      const uint2 u2 = *(const uint2*)(s + (((size_t)b * 512 + c) << 12) + n0 + nn);
      v[r][0] = bflo(u2.x & 0xffffu); v[r][1] = bflo(u2.x >> 16);
      v[r][2] = bflo(u2.y & 0xffffu); v[r][3] = bflo(u2.y >> 16);
    }
  }
  __builtin_amdgcn_sched_barrier(0);   // all loads issued before any use
#pragma unroll
  for (int r = 0; r < 8; ++r) {
    const int c = cbase + r * 64;
#pragma unroll
    for (int k = 0; k < 4; ++k) {
      const unsigned short h = f2bf(v[r][k]);
      Xhi[(nn + k) * 522 + c] = h;
      Xlo[(nn + k) * 522 + c] = f2bf(v[r][k] - bf2f(h));
    }
  }
}

// ---------------------------------------------------------------------------
// Projection tile -> LDS assembly buffers (exact final layouts):
//   QT 16KB: hi[n*256 + d*2] | lo (+8192)          n = local row 0..31
//   KT 16KB: hi[(n*256 + d*2)^((n&7)<<4)] | lo (+8192)
//   VT 32KB: [(c*64 + n*2)^((c&7)<<4)]
// W streamed via 2-deep 4-ks chunk pipeline with explicit vmcnt fences
// (only W loads are outstanding inside the compute phase).
// ---------------------------------------------------------------------------
__device__ __forceinline__ void do_tile2(
    const unsigned short* __restrict__ Whi, const unsigned short* __restrict__ Wlo,
    const float* bsh,
    const unsigned short* Xhi, const unsigned short* Xlo, int fp32mode,
    int wrow0, int kind, int d0,
    int l15, int quad,
    char* __restrict__ QT, char* __restrict__ KT, char* __restrict__ VT)
{
  f32x4 A0, A1, B0, B1, C0, C1;
#pragma unroll
  for (int r = 0; r < 4; ++r) {
    A0[r] = A1[r] = bsh[wrow0 + quad * 4 + r];
    B0[r] = B1[r] = C0[r] = C1[r] = 0.f;
  }
  const unsigned short* whi = Whi + (size_t)(wrow0 + l15) * 512 + quad * 8;
  const unsigned short* wlo = Wlo + (size_t)(wrow0 + l15) * 512 + quad * 8;
  const unsigned short* x0h = Xhi + l15 * 522;
  const unsigned short* x1h = Xhi + (16 + l15) * 522;
  const unsigned short* x0l = Xlo + l15 * 522;
  const unsigned short* x1l = Xlo + (16 + l15) * 522;

  if (fp32mode) {
    bf16x8 h0[4], l0[4], h1[4], l1[4];
#pragma unroll
    for (int j = 0; j < 4; ++j) {
      h0[j] = *(const bf16x8*)(whi + j * 32);
      l0[j] = *(const bf16x8*)(wlo + j * 32);
    }
#pragma unroll
    for (int j = 0; j < 4; ++j) {
      h1[j] = *(const bf16x8*)(whi + (4 + j) * 32);
      l1[j] = *(const bf16x8*)(wlo + (4 + j) * 32);
    }
    __builtin_amdgcn_sched_barrier(0);
    asm volatile("s_waitcnt vmcnt(8)" ::: "memory");
    __builtin_amdgcn_sched_barrier(0);
#pragma unroll
    for (int j = 0; j < 4; ++j) {
      const int o = j * 32 + quad * 8;
      const bf16x8 b0 = *(const bf16x8*)(x0h + o);
      const bf16x8 b1 = *(const bf16x8*)(x1h + o);
      const bf16x8 c0 = *(const bf16x8*)(x0l + o);
      const bf16x8 c1 = *(const bf16x8*)(x1l + o);
      A0 = __builtin_amdgcn_mfma_f32_16x16x32_bf16(h0[j], b0, A0, 0, 0, 0);
      A1 = __builtin_amdgcn_mfma_f32_16x16x32_bf16(h0[j], b1, A1, 0, 0, 0);
      B0 = __builtin_amdgcn_mfma_f32_16x16x32_bf16(h0[j], c0, B0, 0, 0, 0);
      C0 = __builtin_amdgcn_mfma_f32_16x16x32_bf16(l0[j], b0, C0, 0, 0, 0);
      B1 = __builtin_amdgcn_mfma_f32_16x16x32_bf16(h0[j], c1, B1, 0, 0, 0);
      C1 = __builtin_amdgcn_mfma_f32_16x16x32_bf16(l0[j], b1, C1, 0, 0, 0);
    }
#pragma unroll
    for (int j = 0; j < 4; ++j) {
      h0[j] = *(const bf16x8*)(whi + (8 + j) * 32);
      l0[j] = *(const bf16x8*)(wlo + (8 + j) * 32);
    }
    __builtin_amdgcn_sched_barrier(0);
    asm volatile("s_waitcnt vmcnt(8)" ::: "memory");
    __builtin_amdgcn_sched_barrier(0);
#pragma unroll
    for (int j = 0; j < 4; ++j) {
      const int o = (4 + j) * 32 + quad * 8;
      const bf16x8 b0 = *(const bf16x8*)(x0h + o);
      const bf16x8 b1 = *(const bf16x8*)(x1h + o);
      const bf16x8 c0 = *(const bf16x8*)(x0l + o);
      const bf16x8 c1 = *(const bf16x8*)(x1l + o);
      A0 = __builtin_amdgcn_mfma_f32_16x16x32_bf16(h1[j], b0, A0, 0, 0, 0);
      A1 = __builtin_amdgcn_mfma_f32_16x16x32_bf16(h1[j], b1, A1, 0, 0, 0);
      B0 = __builtin_amdgcn_mfma_f32_16x16x32_bf16(h1[j], c0, B0, 0, 0, 0);
      C0 = __builtin_amdgcn_mfma_f32_16x16x32_bf16(l1[j], b0, C0, 0, 0, 0);
      B1 = __builtin_amdgcn_mfma_f32_16x16x32_bf16(h1[j], c1, B1, 0, 0, 0);
      C1 = __builtin_amdgcn_mfma_f32_16x16x32_bf16(l1[j], b1, C1, 0, 0, 0);
    }
#pragma unroll
    for (int j = 0; j < 4; ++j) {
      h1[j] = *(const bf16x8*)(whi + (12 + j) * 32);
      l1[j] = *(const bf16x8*)(wlo + (12 + j) * 32);
    }
    __builtin_amdgcn_sched_barrier(0);
    asm volatile("s_waitcnt vmcnt(8)" ::: "memory");
    __builtin_amdgcn_sched_barrier(0);
#pragma unroll
    for (int j = 0; j < 4; ++j) {
      const int o = (8 + j) * 32 + quad * 8;
      const bf16x8 b0 = *(const bf16x8*)(x0h + o);
      const bf16x8 b1 = *(const bf16x8*)(x1h + o);
      const bf16x8 c0 = *(const bf16x8*)(x0l + o);
      const bf16x8 c1 = *(const bf16x8*)(x1l + o);
      A0 = __builtin_amdgcn_mfma_f32_16x16x32_bf16(h0[j], b0, A0, 0, 0, 0);
      A1 = __builtin_amdgcn_mfma_f32_16x16x32_bf16(h0[j], b1, A1, 0, 0, 0);
      B0 = __builtin_amdgcn_mfma_f32_16x16x32_bf16(h0[j], c0, B0, 0, 0, 0);
      C0 = __builtin_amdgcn_mfma_f32_16x16x32_bf16(l0[j], b0, C0, 0, 0, 0);
      B1 = __builtin_amdgcn_mfma_f32_16x16x32_bf16(h0[j], c1, B1, 0, 0, 0);
      C1 = __builtin_amdgcn_mfma_f32_16x16x32_bf16(l0[j], b1, C1, 0, 0, 0);
    }
    asm volatile("s_waitcnt vmcnt(0)" ::: "memory");
    __builtin_amdgcn_sched_barrier(0);
#pragma unroll
    for (int j = 0; j < 4; ++j) {
      const int o = (12 + j) * 32 + quad * 8;
      const bf16x8 b0 = *(const bf16x8*)(x0h + o);
      const bf16x8 b1 = *(const bf16x8*)(x1h + o);
      const bf16x8 c0 = *(const bf16x8*)(x0l + o);
      const bf16x8 c1 = *(const bf16x8*)(x1l + o);
      A0 = __builtin_amdgcn_mfma_f32_16x16x32_bf16(h1[j], b0, A0, 0, 0, 0);
      A1 = __builtin_amdgcn_mfma_f32_16x16x32_bf16(h1[j], b1, A1, 0, 0, 0);
      B0 = __builtin_amdgcn_mfma_f32_16x16x32_bf16(h1[j], c0, B0, 0, 0, 0);
      C0 = __builtin_amdgcn_mfma_f32_16x16x32_bf16(l1[j], b0, C0, 0, 0, 0);
      B1 = __builtin_amdgcn_mfma_f32_16x16x32_bf16(h1[j], c1, B1, 0, 0, 0);
      C1 = __builtin_amdgcn_mfma_f32_16x16x32_bf16(l1[j], b1, C1, 0, 0, 0);
    }
  } else {
    bf16x8 h0[4], h1[4];
#pragma unroll
    for (int j = 0; j < 4; ++j) h0[j] = *(const bf16x8*)(whi + j * 32);
#pragma unroll
    for (int j = 0; j < 4; ++j) h1[j] = *(const bf16x8*)(whi + (4 + j) * 32);
    __builtin_amdgcn_sched_barrier(0);
    asm volatile("s_waitcnt vmcnt(4)" ::: "memory");
    __builtin_amdgcn_sched_barrier(0);
#pragma unroll
    for (int j = 0; j < 4; ++j) {
      const int o = j * 32 + quad * 8;
      A0 = __builtin_amdgcn_mfma_f32_16x16x32_bf16(h0[j], *(const bf16x8*)(x0h + o), A0, 0, 0, 0);
      A1 = __builtin_amdgcn_mfma_f32_16x16x32_bf16(h0[j], *(const bf16x8*)(x1h + o), A1, 0, 0, 0);
    }
#pragma unroll
    for (int j = 0; j < 4; ++j) h0[j] = *(const bf16x8*)(whi + (8 + j) * 32);
    __builtin_amdgcn_sched_barrier(0);
    asm volatile("s_waitcnt vmcnt(4)" ::: "memory");
    __builtin_amdgcn_sched_barrier(0);
#pragma unroll
    for (int j = 0; j < 4; ++j) {
      const int o = (4 + j) * 32 + quad * 8;
      A0 = __builtin_amdgcn_mfma_f32_16x16x32_bf16(h1[j], *(const bf16x8*)(x0h + o), A0, 0, 0, 0);
      A1 = __builtin_amdgcn_mfma_f32_16x16x32_bf16(h1[j], *(const bf16x8*)(x1h + o), A1, 0, 0, 0);
    }
#pragma unroll
    for (int j = 0; j < 4; ++j) h1[j] = *(const bf16x8*)(whi + (12 + j) * 32);
    __builtin_amdgcn_sched_barrier(0);
    asm volatile("s_waitcnt vmcnt(4)" ::: "memory");
    __builtin_amdgcn_sched_barrier(0);
#pragma unroll
    for (int j = 0; j < 4; ++j) {
      const int o = (8 + j) * 32 + quad * 8;
      A0 = __builtin_amdgcn_mfma_f32_16x16x32_bf16(h0[j], *(const bf16x8*)(x0h + o), A0, 0, 0, 0);
      A1 = __builtin_amdgcn_mfma_f32_16x16x32_bf16(h0[j], *(const bf16x8*)(x1h + o), A1, 0, 0, 0);
    }
    asm volatile("s_waitcnt vmcnt(0)" ::: "memory");
    __builtin_amdgcn_sched_barrier(0);
#pragma unroll
    for (int j = 0; j < 4; ++j) {
      const int o = (12 + j) * 32 + quad * 8;
      A0 = __builtin_amdgcn_mfma_f32_16x16x32_bf16(h1[j], *(const bf16x8*)(x0h + o), A0, 0, 0, 0);
      A1 = __builtin_amdgcn_mfma_f32_16x16x32_bf16(h1[j], *(const bf16x8*)(x1h + o), A1, 0, 0, 0);
    }
  }

  const f32x4 a0 = fp32mode ? (A0 + B0) + C0 : A0;
  const f32x4 a1 = fp32mode ? (A1 + B1) + C1 : A1;
#pragma unroll
  for (int ns = 0; ns < 2; ++ns) {
    const f32x4 acc = ns ? a1 : a0;
    const int n = ns * 16 + l15;                 // local row
    if (kind <= 1) {                             // Q or K
      ushort4 h, l;
#pragma unroll
      for (int r = 0; r < 4; ++r) {
        const float f = acc[r];
        const unsigned short hh = f2bf(f);
        ((unsigned short*)&h)[r] = hh;
        ((unsigned short*)&l)[r] = f2bf(f - bf2f(hh));
      }
      const unsigned lin = (unsigned)(n * 256 + (d0 + quad * 4) * 2);
      if (kind == 0) {
        *(ushort4*)(QT + lin) = h;
        *(ushort4*)(QT + 8192 + lin) = l;
      } else {
        const unsigned off = lin ^ ((unsigned)(n & 7) << 4);
        *(ushort4*)(KT + off) = h;
        *(ushort4*)(KT + 8192 + off) = l;
      }
    } else {                                     // V
#pragma unroll
      for (int r = 0; r < 4; ++r) {
        const int c = d0 + quad * 4 + r;
        const unsigned off =
            ((unsigned)(c * 64 + n * 2)) ^ ((unsigned)(c & 7) << 4);
        *(unsigned short*)(VT + off) = f2bf(acc[r]);
      }
    }
  }
}

__global__ __launch_bounds__(512, 2) void proj_kernel(
    const void* __restrict__ x, const void* __restrict__ dep,
    const unsigned short* __restrict__ Whi, const unsigned short* __restrict__ Wlo,
    const float* __restrict__ Bcat,
    unsigned short* __restrict__ Qhi, unsigned short* __restrict__ Qlo,
    unsigned short* __restrict__ Kst, unsigned short* __restrict__ Vst)
{
  __shared__ unsigned short Xhi[32 * 522];   // 33.4 KB (stride 522: bank spread)
  __shared__ unsigned short Xlo[32 * 522];
  __shared__ char QT[16384];                 // Q tile: hi 8K | lo 8K
  __shared__ char KT[16384];                 // K tile: hi 8K | lo 8K (swizzled)
  __shared__ char VT[32768];                 // V tile (swizzled)
  __shared__ float bsh[768];
  const int fp32mode = detect_fp32_mode(x);
  const int tid  = threadIdx.x;
  const int lane = tid & 63;
  const int w    = tid >> 6;           // 0..7
  const int l15  = lane & 15;
  const int quad = lane >> 4;
  const int b  = blockIdx.y;
  const int t  = blockIdx.x;           // n-tile index (32 rows)
  const int n0 = t * 32;

  const int cbase = tid >> 3;          // 0..63
  const int nn    = (tid & 7) * 4;

  for (int i = tid; i < 768; i += 512) bsh[i] = Bcat[i];

  // ---- stage X (from x), fenced batch ----
  stage_X(x, fp32mode, b, n0, cbase, nn, Xhi, Xlo);
  __syncthreads();

  // ---- stage-1 (from x): 40 tiles = wq(4) | wk(4) | wv(32); wave stride 8 ----
  for (int rt = w; rt < 40; rt += 8) {
    if (rt < 4)
      do_tile2(Whi, Wlo, bsh, Xhi, Xlo, fp32mode, rt * 16,             0, rt * 16,
               l15, quad, QT, KT, VT);
    else if (rt < 8)
      do_tile2(Whi, Wlo, bsh, Xhi, Xlo, fp32mode, 128 + (rt - 4) * 16, 1, (rt - 4) * 16,
               l15, quad, QT, KT, VT);
    else
      do_tile2(Whi, Wlo, bsh, Xhi, Xlo, fp32mode, 256 + (rt - 8) * 16, 2, (rt - 8) * 16,
               l15, quad, QT, KT, VT);
  }
  __syncthreads();

  // ---- dump V (coalesced 16B), then stage X (from dep), fenced batch ----
  {
    char* vdst = (char*)Vst + (((size_t)b * 128 + t) << 15);
#pragma unroll
    for (int i = 0; i < 4; ++i) {
      const int off = i * 8192 + tid * 16;
      *(uint4*)(vdst + off) = *(const uint4*)(VT + off);
    }
  }
  stage_X(dep, fp32mode, b, n0, cbase, nn, Xhi, Xlo);
  __syncthreads();

  // ---- stage-2 (from dep): wqd(4) | wkd(4), one tile per wave, d-base 64 ----
  {
    const int rt = w;
    if (rt < 4)
      do_tile2(Whi, Wlo, bsh, Xhi, Xlo, fp32mode, 64 + rt * 16,        0, 64 + rt * 16,
               l15, quad, QT, KT, VT);
    else
      do_tile2(Whi, Wlo, bsh, Xhi, Xlo, fp32mode, 192 + (rt - 4) * 16, 1, 64 + (rt - 4) * 16,
               l15, quad, QT, KT, VT);
  }
  __syncthreads();

  // ---- dump Q + K (coalesced 16B) ----
  {
    char* kdst = (char*)Kst + (((size_t)b * 128 + t) << 14);
#pragma unroll
    for (int i = 0; i < 2; ++i) {
      const int off = i * 8192 + tid * 16;
      *(uint4*)(kdst + off) = *(const uint4*)(KT + off);
    }
    const size_t qoff = ((((size_t)b << 12) + n0) * 128) * 2;   // bytes
    *(uint4*)((char*)Qhi + qoff + tid * 16) = *(const uint4*)(QT + tid * 16);
    *(uint4*)((char*)Qlo + qoff + tid * 16) = *(const uint4*)(QT + 8192 + tid * 16);
  }
}

// ---------------------------------------------------------------------------
// Producer/consumer flash attention (unchanged from round 10).
// Grid: 256 blocks x 768 thr (12 waves). Block = 64 rows of one batch.
// Waves 0..3: energy; waves 4..11: PV (64-ch slice owner). 1 barrier/iter,
// P[2] parity dbuf, counted vmcnt per role, setprio on MFMA clusters.
// LDS: KL 32K + VL 64K + P 10K + lstat = 106.5K -> 1 block/CU, 3 waves/SIMD.
// ---------------------------------------------------------------------------
__global__ __launch_bounds__(768, 3) void attn_kernel(
    const unsigned short* __restrict__ Qhi, const unsigned short* __restrict__ Qlo,
    const unsigned short* __restrict__ Kst, const unsigned short* __restrict__ Vst,
    const void* __restrict__ x, const float* __restrict__ gamF,
    void* __restrict__ outp)
{
  __shared__ char KL[2][16384];          // [buf][hi 8KB | lo 8KB] swizzled
  __shared__ char VL[2][32768];          // [buf][512c x 32j] swizzled
  __shared__ unsigned short P[2][64][40];// [buf][i][j] stride 80B
  __shared__ float lstat[2][4][16];      // [jt][itg][row]

  const int fp32mode = detect_fp32_mode(x);
  const int tid  = threadIdx.x;
  const int lane = tid & 63;
  const int w    = tid >> 6;          // 0..11
  const int l15  = lane & 15;
  const int quad = lane >> 4;
  const int id   = blockIdx.x;
  const int b    = (id >> 1) & 3;
  const int n0   = (((id >> 3) << 1) | (id & 1)) * 64;

  // Force fp32mode's global loads to fully retire before any gld16 below,
  // so the counted-vmcnt FIFO sees only staging loads.
  asm volatile("" :: "v"(fp32mode) : "memory");

  const char* Kb = (const char*)Kst + (((size_t)b * 128) << 14);
  const char* Vb = (const char*)Vst + (((size_t)b * 128) << 15);

  if (w < 4) {
    // =========================== ENERGY ROLE ===========================
    const int ihE = w >> 1;            // 32-row half of the 64-row block
    const int jt  = w & 1;             // 16-j half of the 32-j tile
    bf16x8 qh[2][4], ql[2][4];
#pragma unroll
    for (int itq = 0; itq < 2; ++itq) {
      const size_t qb =
          (((size_t)b << 12) + n0 + ihE * 32 + itq * 16 + l15) * 128 + quad * 8;
#pragma unroll
      for (int ds = 0; ds < 4; ++ds) {
        qh[itq][ds] = *(const bf16x8*)(Qhi + qb + ds * 32);
        ql[itq][ds] = *(const bf16x8*)(Qlo + qb + ds * 32);
      }
    }
    // prologue: stage K(0) -> KL[0] (4 chunks of 1KB)
#pragma unroll
    for (int ch = 0; ch < 4; ++ch) {
      const int c = w + ch * 4;
      gld16(Kb + c * 1024 + lane * 16, &KL[0][c * 1024]);
    }
    float lpart[2] = {0.f, 0.f};

    for (int t = 0; t <= 128; ++t) {
      asm volatile("s_waitcnt vmcnt(0) lgkmcnt(0)" ::: "memory");
      __builtin_amdgcn_sched_barrier(0);
      __builtin_amdgcn_s_barrier();
      __builtin_amdgcn_sched_barrier(0);
      if (t < 128) {
        const int cur = t & 1;
        if (t < 127) {                 // stage K(t+1) -> KL[nxt]
          const char* src = Kb + ((size_t)(t + 1) << 14);
#pragma unroll
          for (int ch = 0; ch < 4; ++ch) {
            const int c = w + ch * 4;
            gld16(src + c * 1024 + lane * 16, &KL[cur ^ 1][c * 1024]);
          }
        }
        __builtin_amdgcn_sched_barrier(0);
        const int row = jt * 16 + l15;
        const unsigned rsw = (unsigned)(row & 7) << 4;
        const char* kb = &KL[cur][0];
        bf16x8 kh[4], kl[4];
#pragma unroll
        for (int ds = 0; ds < 4; ++ds) {
          const unsigned off = ((unsigned)(row * 256 + quad * 16 + ds * 64)) ^ rsw;
          kh[ds] = *(const bf16x8*)(kb + off);
          kl[ds] = *(const bf16x8*)(kb + 8192 + off);
        }
        f32x4 ea[2], eb[2], ec[2];
#pragma unroll
        for (int itq = 0; itq < 2; ++itq) {
          ea[itq] = (f32x4){0.f, 0.f, 0.f, 0.f};
          eb[itq] = (f32x4){0.f, 0.f, 0.f, 0.f};
          ec[itq] = (f32x4){0.f, 0.f, 0.f, 0.f};
        }
        __builtin_amdgcn_s_setprio(1);
#pragma unroll
        for (int ds = 0; ds < 4; ++ds)
#pragma unroll
          for (int itq = 0; itq < 2; ++itq) {
            ea[itq] = __builtin_amdgcn_mfma_f32_16x16x32_bf16(kh[ds], qh[itq][ds], ea[itq], 0, 0, 0);
            eb[itq] = __builtin_amdgcn_mfma_f32_16x16x32_bf16(kh[ds], ql[itq][ds], eb[itq], 0, 0, 0);
            ec[itq] = __builtin_amdgcn_mfma_f32_16x16x32_bf16(kl[ds], qh[itq][ds], ec[itq], 0, 0, 0);
          }
        __builtin_amdgcn_s_setprio(0);
#pragma unroll
        for (int itq = 0; itq < 2; ++itq) {
          const f32x4 e = (ea[itq] + eb[itq]) + ec[itq];
          const float p0 = __expf(e[0] - 32.0f);
          const float p1 = __expf(e[1] - 32.0f);
          const float p2 = __expf(e[2] - 32.0f);
          const float p3 = __expf(e[3] - 32.0f);
          const unsigned short u0 = f2bf(p0), u1 = f2bf(p1);
          const unsigned short u2 = f2bf(p2), u3 = f2bf(p3);
          lpart[itq] += (bf2f(u0) + bf2f(u1)) + (bf2f(u2) + bf2f(u3));
          unsigned int* dst = (unsigned int*)
              (&P[cur][ihE * 32 + itq * 16 + l15][jt * 16 + quad * 4]);
          dst[0] = (unsigned int)u0 | ((unsigned int)u1 << 16);
          dst[1] = (unsigned int)u2 | ((unsigned int)u3 << 16);
        }
      }
    }
    // l partials -> lstat
#pragma unroll
    for (int itq = 0; itq < 2; ++itq) {
      float lp = lpart[itq];
      lp += __shfl_xor(lp, 16, 64);
      lp += __shfl_xor(lp, 32, 64);
      if (quad == 0) lstat[jt][ihE * 2 + itq][l15] = lp;
    }
    __syncthreads();
    return;
  }

  // ============================= PV ROLE ==============================
  const int wv = w - 4;                // 64-channel slice owner
#pragma unroll
  for (int k = 0; k < 4; ++k) {
    const int c = wv * 4 + k;
    gld16(Vb + c * 1024 + lane * 16, &VL[0][c * 1024]);
  }
  f32x4 acc[4][4];                     // [ct][itv] = 64 regs
#pragma unroll
  for (int ct = 0; ct < 4; ++ct)
#pragma unroll
    for (int itv = 0; itv < 4; ++itv) acc[ct][itv] = (f32x4){0.f, 0.f, 0.f, 0.f};

  for (int t = 0; t <= 128; ++t) {
    if (t <= 127)
      asm volatile("s_waitcnt vmcnt(4)" ::: "memory");
    else
      asm volatile("s_waitcnt vmcnt(0)" ::: "memory");
    __builtin_amdgcn_sched_barrier(0);
    __builtin_amdgcn_s_barrier();
    __builtin_amdgcn_sched_barrier(0);
    if (t >= 1) {
      const int pb = (t - 1) & 1;
      bf16x8 pf[4];
#pragma unroll
      for (int itv = 0; itv < 4; ++itv)
        pf[itv] = *(const bf16x8*)(&P[pb][itv * 16 + l15][quad * 8]);
      const char* vb = &VL[pb][0];
      __builtin_amdgcn_s_setprio(1);
#pragma unroll
      for (int ct = 0; ct < 4; ++ct) {
        const int c = wv * 64 + ct * 16 + l15;
        const unsigned off =
            ((unsigned)(c * 64 + quad * 16)) ^ ((unsigned)(c & 7) << 4);
        const bf16x8 va = *(const bf16x8*)(vb + off);
#pragma unroll
        for (int itv = 0; itv < 4; ++itv)
          acc[ct][itv] = __builtin_amdgcn_mfma_f32_16x16x32_bf16(va, pf[itv], acc[ct][itv], 0, 0, 0);
      }
      __builtin_amdgcn_s_setprio(0);
      __builtin_amdgcn_sched_barrier(0);
    }
    if (t < 127) {                     // stage V(t+1) own slice (post-read)
      const char* src = Vb + ((size_t)(t + 1) << 15);
#pragma unroll
      for (int k = 0; k < 4; ++k) {
        const int c = wv * 4 + k;
        gld16(src + c * 1024 + lane * 16, &VL[(t + 1) & 1][c * 1024]);
      }
    }
  }
  __syncthreads();

  // ---- epilogue: out[c][n] = gamma*O/l + x for my 64-channel slice ----
  const float gv = gamF[0];
  float sc[4];
#pragma unroll
  for (int itv = 0; itv < 4; ++itv) {
    const float l = lstat[0][itv][l15] + lstat[1][itv][l15];
    sc[itv] = gv / l;
  }
#pragma unroll
  for (int ct = 0; ct < 4; ++ct)
#pragma unroll
    for (int r = 0; r < 4; ++r) {
      const int c_g = wv * 64 + ct * 16 + quad * 4 + r;
      const size_t brow = ((size_t)b * 512 + c_g) << 12;
#pragma unroll
      for (int itv = 0; itv < 4; ++itv) {
        const size_t addr = brow + n0 + itv * 16 + l15;
        const float o = sc[itv] * acc[ct][itv][r];
        if (fp32mode) {
          ((float*)outp)[addr] = o + ((const float*)x)[addr];
        } else {
          ((unsigned short*)outp)[addr] =
              f2bf(o + bf2f(((const unsigned short*)x)[addr]));
        }
      }
    }
}

extern "C" void kernel_launch(void* const* d_in, const int* in_sizes, int n_in,
                              void* d_out, int out_size, void* d_ws, size_t ws_size,
                              hipStream_t stream) {
  const void* x    = d_in[0];
  const void* dep  = d_in[1];
  const void* wq   = d_in[2];
  const void* bq   = d_in[3];
  const void* wqd  = d_in[4];
  const void* bqd  = d_in[5];
  const void* wk   = d_in[6];
  const void* bk   = d_in[7];
  const void* wkd  = d_in[8];
  const void* bkd  = d_in[9];
  const void* wv   = d_in[10];
  const void* bv   = d_in[11];
  const void* gam  = d_in[12];

  // ws: Whi(768K) Wlo(768K) Bcat gamF | @2M Qhi 4M | @6M Qlo 4M
  //     | @10M Kst 8M (tiled+swizzled) | @18M Vst 16M (tiled+swizzled)
  unsigned short* Whi = (unsigned short*)d_ws;
  unsigned short* Wlo = Whi + (size_t)768 * 512;
  float* Bcat = (float*)(Wlo + (size_t)768 * 512);
  float* gamF = Bcat + 768;
  unsigned short* Qhi = (unsigned short*)((char*)d_ws + ((size_t)2 << 20));
  unsigned short* Qlo = (unsigned short*)((char*)d_ws + ((size_t)6 << 20));
  unsigned short* Kst = (unsigned short*)((char*)d_ws + ((size_t)10 << 20));
  unsigned short* Vst = (unsigned short*)((char*)d_ws + ((size_t)18 << 20));

  prep_kernel<<<768, 256, 0, stream>>>(wq, bq, wqd, bqd, wk, bk, wkd, bkd,
                                       wv, bv, gam, x, Whi, Wlo, Bcat, gamF);
  proj_kernel<<<dim3(128, 4), 512, 0, stream>>>(x, dep, Whi, Wlo, Bcat,
                                                Qhi, Qlo, Kst, Vst);
  attn_kernel<<<256, 768, 0, stream>>>(Qhi, Qlo, Kst, Vst, x, gamF, d_out);
}

// Round 10
// 436.167 us; speedup vs baseline: 1.0774x; 1.0002x over previous
//
#include <hip/hip_runtime.h>

// ---------------------------------------------------------------------------
// PAM_Module_Dep: dual-modality position attention. B=4, C=512, N=4096, CQ=64.
// Round 15: proj code-size collapse (attn unchanged from round 10).
//   Rounds 10-14 evidence: five structurally different proj kernels (varying
//   the ENTIRE memory pattern) all 203-240us; work floors sum to ~25us ->
//   the shared invariant is ~100KB of fully-unrolled straight-line code
//   executed once per block = cold I-fetch bound (attn's compact 128x loop
//   is fine on identical machinery).
// Fix: (1) compact do_tile with runtime kind + real ks-loop (unroll 2,
//   1-deep W preload) -> ~8KB body; (2) grid 512->256 blocks, 2 tiles per
//   block via rep loop -> all blocks resident, rep 1 runs with hot I-cache.
// Math bit-identical: same chain order (A/B/C over ks, (A+B)+C), same
//   stage_X conversion, same swizzled output layouts.
// attn: producer/consumer wave specialization (r10): 4 energy waves + 8 PV
//   waves, 1 barrier/iter, counted vmcnt, P parity dbuf. Math retained:
//   constant mhat=32, split-bf16 exact energy (hh+hl+lh), p rounded to bf16
//   with l summed from rounded p, O^T=V^T*P^T, out = gamma*O/l + x.
// ---------------------------------------------------------------------------

typedef __attribute__((ext_vector_type(8))) short bf16x8;
typedef __attribute__((ext_vector_type(4))) float f32x4;

__device__ __forceinline__ float bf2f(unsigned short u) {
  return __builtin_bit_cast(float, (unsigned int)u << 16);
}
__device__ __forceinline__ unsigned short f2bf(float f) {
  unsigned int u = __builtin_bit_cast(unsigned int, f);
  u = u + 0x7fffu + ((u >> 16) & 1u);   // RNE
  return (unsigned short)(u >> 16);
}
__device__ __forceinline__ float bflo(unsigned int u) {
  return __builtin_bit_cast(float, u << 16);
}

// Async 16B/lane global->LDS DMA (wave writes ldsbase + lane*16).
__device__ __forceinline__ void gld16(const char* g, char* l) {
  __builtin_amdgcn_global_load_lds(
      (const __attribute__((address_space(1))) unsigned int*)g,
      (__attribute__((address_space(3))) unsigned int*)l, 16, 0, 0);
}

// Returns 1 if x looks like fp32 data, 0 if bf16. Wave-uniform, deterministic.
__device__ __forceinline__ int detect_fp32_mode(const void* xv) {
  const unsigned int* p = (const unsigned int*)xv;
  const int lane = threadIdx.x & 63;
  const unsigned int w0 = p[lane];
  const unsigned int w1 = p[64 + lane];
  int cnt = 0;
  const unsigned short us[4] = {
      (unsigned short)(w0 & 0xffffu), (unsigned short)(w0 >> 16),
      (unsigned short)(w1 & 0xffffu), (unsigned short)(w1 >> 16)};
#pragma unroll
  for (int h = 0; h < 4; ++h) {
    const float a = fabsf(bf2f(us[h]));
    cnt += (a > 9.0e-13f && a < 32.0f) ? 1 : 0;
  }
#pragma unroll
  for (int mm = 32; mm >= 1; mm >>= 1) cnt += __shfl_xor(cnt, mm, 64);
  return cnt < 220;
}

// ---------------------------------------------------------------------------
// prep: canonicalize weights into ws as split hi/lo bf16; biases+gamma fp32.
// ---------------------------------------------------------------------------
__global__ __launch_bounds__(256) void prep_kernel(
    const void* wq, const void* bq, const void* wqd, const void* bqd,
    const void* wk, const void* bk, const void* wkd, const void* bkd,
    const void* wv, const void* bv, const void* gam, const void* x,
    unsigned short* __restrict__ Whi, unsigned short* __restrict__ Wlo,
    float* __restrict__ Bcat, float* __restrict__ gamF)
{
  const int fp32mode = detect_fp32_mode(x);
  const int row = blockIdx.x;                    // 0..767
  const void* src; const void* bsrc; int srow;
  if (row < 64)       { src = wq;  bsrc = bq;  srow = row; }
  else if (row < 128) { src = wqd; bsrc = bqd; srow = row - 64; }
  else if (row < 192) { src = wk;  bsrc = bk;  srow = row - 128; }
  else if (row < 256) { src = wkd; bsrc = bkd; srow = row - 192; }
  else                { src = wv;  bsrc = bv;  srow = row - 256; }
  for (int c = threadIdx.x; c < 512; c += 256) {
    const float v = fp32mode ? ((const float*)src)[(size_t)srow * 512 + c]
                             : bf2f(((const unsigned short*)src)[(size_t)srow * 512 + c]);
    const unsigned short h = f2bf(v);
    Whi[(size_t)row * 512 + c] = h;
    Wlo[(size_t)row * 512 + c] = f2bf(v - bf2f(h));
  }
  if (threadIdx.x == 0) {
    Bcat[row] = fp32mode ? ((const float*)bsrc)[srow]
                         : bf2f(((const unsigned short*)bsrc)[srow]);
    if (row == 0)
      gamF[0] = fp32mode ? ((const float*)gam)[0]
                         : bf2f(((const unsigned short*)gam)[0]);
  }
}

// ---------------------------------------------------------------------------
// Batched X staging (fenced): 8 loads -> static regs, fence, convert+write.
// cbase = tid>>3 (0..63), nn = (tid&7)*4.
// ---------------------------------------------------------------------------
__device__ __forceinline__ void stage_X(
    const void* __restrict__ src, int fp32mode, int b, int n0,
    int cbase, int nn,
    unsigned short* __restrict__ Xhi, unsigned short* __restrict__ Xlo)
{
  float v[8][4];
  if (fp32mode) {
    const float* s = (const float*)src;
#pragma unroll
    for (int r = 0; r < 8; ++r) {
      const int c = cbase + r * 64;
      const float4 f4 = *(const float4*)(s + (((size_t)b * 512 + c) << 12) + n0 + nn);
      v[r][0] = f4.x; v[r][1] = f4.y; v[r][2] = f4.z; v[r][3] = f4.w;
    }
  } else {
    const unsigned short* s = (const unsigned short*)src;
#pragma unroll
    for (int r = 0; r < 8; ++r) {
      const int c = cbase + r * 64;
      const uint2 u2 = *(const uint2*)(s + (((size_t)b * 512 + c) << 12) + n0 + nn);
      v[r][0] = bflo(u2.x & 0xffffu); v[r][1] = bflo(u2.x >> 16);
      v[r][2] = bflo(u2.y & 0xffffu); v[r][3] = bflo(u2.y >> 16);
    }
  }
  __builtin_amdgcn_sched_barrier(0);   // all loads issued before any use
#pragma unroll
  for (int r = 0; r < 8; ++r) {
    const int c = cbase + r * 64;
#pragma unroll
    for (int k = 0; k < 4; ++k) {
      const unsigned short h = f2bf(v[r][k]);
      Xhi[(nn + k) * 522 + c] = h;
      Xlo[(nn + k) * 522 + c] = f2bf(v[r][k] - bf2f(h));
    }
  }
}

// ---------------------------------------------------------------------------
// COMPACT projection tile (round-15). Runtime kind, real ks-loop (unroll 2),
// 1-deep W preload. Output layouts identical to r10-14:
//   QT 16KB: hi[n*256 + d*2] | lo (+8192)
//   KT 16KB: hi[(n*256 + d*2)^((n&7)<<4)] | lo (+8192)
//   VT 32KB: [(c*64 + n*2)^((c&7)<<4)]
// ---------------------------------------------------------------------------
__device__ __forceinline__ void do_tile_c(
    const unsigned short* __restrict__ Whi, const unsigned short* __restrict__ Wlo,
    const float* bsh,
    const unsigned short* Xhi, const unsigned short* Xlo, int fp32mode,
    int wrow0, int kind, int d0,
    int l15, int quad,
    char* __restrict__ QT, char* __restrict__ KT, char* __restrict__ VT)
{
  f32x4 A0, A1, B0, B1, C0, C1;
#pragma unroll
  for (int r = 0; r < 4; ++r) {
    A0[r] = A1[r] = bsh[wrow0 + quad * 4 + r];
    B0[r] = B1[r] = C0[r] = C1[r] = 0.f;
  }
  const unsigned short* wh_p = Whi + (size_t)(wrow0 + l15) * 512 + quad * 8;
  const unsigned short* wl_p = Wlo + (size_t)(wrow0 + l15) * 512 + quad * 8;
  const unsigned short* x0h = Xhi + l15 * 522 + quad * 8;
  const unsigned short* x1h = Xhi + (16 + l15) * 522 + quad * 8;
  const unsigned short* x0l = Xlo + l15 * 522 + quad * 8;
  const unsigned short* x1l = Xlo + (16 + l15) * 522 + quad * 8;

  bf16x8 hc = *(const bf16x8*)(wh_p);
  bf16x8 lc;
  if (fp32mode) lc = *(const bf16x8*)(wl_p);

#pragma unroll 2
  for (int ks = 0; ks < 16; ++ks) {
    bf16x8 hn, ln;
    if (ks < 15) {
      hn = *(const bf16x8*)(wh_p + (ks + 1) * 32);
      if (fp32mode) ln = *(const bf16x8*)(wl_p + (ks + 1) * 32);
    }
    const int o = ks * 32;
    const bf16x8 b0 = *(const bf16x8*)(x0h + o);
    const bf16x8 b1 = *(const bf16x8*)(x1h + o);
    A0 = __builtin_amdgcn_mfma_f32_16x16x32_bf16(hc, b0, A0, 0, 0, 0);
    A1 = __builtin_amdgcn_mfma_f32_16x16x32_bf16(hc, b1, A1, 0, 0, 0);
    if (fp32mode) {
      const bf16x8 c0 = *(const bf16x8*)(x0l + o);
      const bf16x8 c1 = *(const bf16x8*)(x1l + o);
      B0 = __builtin_amdgcn_mfma_f32_16x16x32_bf16(hc, c0, B0, 0, 0, 0);
      C0 = __builtin_amdgcn_mfma_f32_16x16x32_bf16(lc, b0, C0, 0, 0, 0);
      B1 = __builtin_amdgcn_mfma_f32_16x16x32_bf16(hc, c1, B1, 0, 0, 0);
      C1 = __builtin_amdgcn_mfma_f32_16x16x32_bf16(lc, b1, C1, 0, 0, 0);
    }
    if (ks < 15) { hc = hn; if (fp32mode) lc = ln; }
  }

  const f32x4 a0 = fp32mode ? (A0 + B0) + C0 : A0;
  const f32x4 a1 = fp32mode ? (A1 + B1) + C1 : A1;
#pragma unroll
  for (int ns = 0; ns < 2; ++ns) {
    const f32x4 acc = ns ? a1 : a0;
    const int n = ns * 16 + l15;                 // local row
    if (kind <= 1) {                             // Q or K
      ushort4 h, l;
#pragma unroll
      for (int r = 0; r < 4; ++r) {
        const float f = acc[r];
        const unsigned short hh = f2bf(f);
        ((unsigned short*)&h)[r] = hh;
        ((unsigned short*)&l)[r] = f2bf(f - bf2f(hh));
      }
      const unsigned lin = (unsigned)(n * 256 + (d0 + quad * 4) * 2);
      if (kind == 0) {
        *(ushort4*)(QT + lin) = h;
        *(ushort4*)(QT + 8192 + lin) = l;
      } else {
        const unsigned off = lin ^ ((unsigned)(n & 7) << 4);
        *(ushort4*)(KT + off) = h;
        *(ushort4*)(KT + 8192 + off) = l;
      }
    } else {                                     // V
#pragma unroll
      for (int r = 0; r < 4; ++r) {
        const int c = d0 + quad * 4 + r;
        const unsigned off =
            ((unsigned)(c * 64 + n * 2)) ^ ((unsigned)(c & 7) << 4);
        *(unsigned short*)(VT + off) = f2bf(acc[r]);
      }
    }
  }
}

__global__ __launch_bounds__(512, 2) void proj_kernel(
    const void* __restrict__ x, const void* __restrict__ dep,
    const unsigned short* __restrict__ Whi, const unsigned short* __restrict__ Wlo,
    const float* __restrict__ Bcat,
    unsigned short* __restrict__ Qhi, unsigned short* __restrict__ Qlo,
    unsigned short* __restrict__ Kst, unsigned short* __restrict__ Vst)
{
  __shared__ unsigned short Xhi[32 * 522];   // 33.4 KB (stride 522: bank spread)
  __shared__ unsigned short Xlo[32 * 522];
  __shared__ char QT[16384];                 // Q tile: hi 8K | lo 8K
  __shared__ char KT[16384];                 // K tile: hi 8K | lo 8K (swizzled)
  __shared__ char VT[32768];                 // V tile (swizzled)
  __shared__ float bsh[768];
  const int fp32mode = detect_fp32_mode(x);
  const int tid  = threadIdx.x;
  const int lane = tid & 63;
  const int w    = tid >> 6;           // 0..7
  const int l15  = lane & 15;
  const int quad = lane >> 4;
  const int b  = blockIdx.y;

  const int cbase = tid >> 3;          // 0..63
  const int nn    = (tid & 7) * 4;

  for (int i = tid; i < 768; i += 512) bsh[i] = Bcat[i];

  // Two tiles per block (all 256 blocks resident; rep 1 runs with hot I$).
  for (int rep = 0; rep < 2; ++rep) {
    const int t  = blockIdx.x + rep * 64;  // n-tile index (32 rows)
    const int n0 = t * 32;

    // ---- stage X (from x), fenced batch ----
    stage_X(x, fp32mode, b, n0, cbase, nn, Xhi, Xlo);
    __syncthreads();

    // ---- stage-1 (from x): 40 tiles = wq(4) | wk(4) | wv(32) ----
    for (int rt = w; rt < 40; rt += 8) {
      int wrow0, kind, d0;
      if (rt < 4)      { wrow0 = rt * 16;             kind = 0; d0 = rt * 16; }
      else if (rt < 8) { wrow0 = 128 + (rt - 4) * 16; kind = 1; d0 = (rt - 4) * 16; }
      else             { wrow0 = 256 + (rt - 8) * 16; kind = 2; d0 = (rt - 8) * 16; }
      do_tile_c(Whi, Wlo, bsh, Xhi, Xlo, fp32mode, wrow0, kind, d0,
                l15, quad, QT, KT, VT);
    }
    __syncthreads();

    // ---- dump V (coalesced 16B), then stage X (from dep) ----
    {
      char* vdst = (char*)Vst + (((size_t)b * 128 + t) << 15);
#pragma unroll
      for (int i = 0; i < 4; ++i) {
        const int off = i * 8192 + tid * 16;
        *(uint4*)(vdst + off) = *(const uint4*)(VT + off);
      }
    }
    stage_X(dep, fp32mode, b, n0, cbase, nn, Xhi, Xlo);
    __syncthreads();

    // ---- stage-2 (from dep): wqd(4) | wkd(4), one tile per wave ----
    {
      const int rt = w;
      const int kind  = (rt < 4) ? 0 : 1;
      const int wrow0 = (rt < 4) ? 64 + rt * 16 : 192 + (rt - 4) * 16;
      const int d0    = 64 + (rt & 3) * 16;
      do_tile_c(Whi, Wlo, bsh, Xhi, Xlo, fp32mode, wrow0, kind, d0,
                l15, quad, QT, KT, VT);
    }
    __syncthreads();

    // ---- dump Q + K (coalesced 16B) ----
    {
      char* kdst = (char*)Kst + (((size_t)b * 128 + t) << 14);
#pragma unroll
      for (int i = 0; i < 2; ++i) {
        const int off = i * 8192 + tid * 16;
        *(uint4*)(kdst + off) = *(const uint4*)(KT + off);
      }
      const size_t qoff = ((((size_t)b << 12) + n0) * 128) * 2;   // bytes
      *(uint4*)((char*)Qhi + qoff + tid * 16) = *(const uint4*)(QT + tid * 16);
      *(uint4*)((char*)Qlo + qoff + tid * 16) = *(const uint4*)(QT + 8192 + tid * 16);
    }
    __syncthreads();   // QT/KT/VT reads drained before next rep overwrites
  }
}

// ---------------------------------------------------------------------------
// Producer/consumer flash attention (unchanged from round 10).
// Grid: 256 blocks x 768 thr (12 waves). Block = 64 rows of one batch.
// Waves 0..3: energy; waves 4..11: PV (64-ch slice owner). 1 barrier/iter,
// P[2] parity dbuf, counted vmcnt per role, setprio on MFMA clusters.
// LDS: KL 32K + VL 64K + P 10K + lstat = 106.5K -> 1 block/CU, 3 waves/SIMD.
// ---------------------------------------------------------------------------
__global__ __launch_bounds__(768, 3) void attn_kernel(
    const unsigned short* __restrict__ Qhi, const unsigned short* __restrict__ Qlo,
    const unsigned short* __restrict__ Kst, const unsigned short* __restrict__ Vst,
    const void* __restrict__ x, const float* __restrict__ gamF,
    void* __restrict__ outp)
{
  __shared__ char KL[2][16384];          // [buf][hi 8KB | lo 8KB] swizzled
  __shared__ char VL[2][32768];          // [buf][512c x 32j] swizzled
  __shared__ unsigned short P[2][64][40];// [buf][i][j] stride 80B
  __shared__ float lstat[2][4][16];      // [jt][itg][row]

  const int fp32mode = detect_fp32_mode(x);
  const int tid  = threadIdx.x;
  const int lane = tid & 63;
  const int w    = tid >> 6;          // 0..11
  const int l15  = lane & 15;
  const int quad = lane >> 4;
  const int id   = blockIdx.x;
  const int b    = (id >> 1) & 3;
  const int n0   = (((id >> 3) << 1) | (id & 1)) * 64;

  // Force fp32mode's global loads to fully retire before any gld16 below,
  // so the counted-vmcnt FIFO sees only staging loads.
  asm volatile("" :: "v"(fp32mode) : "memory");

  const char* Kb = (const char*)Kst + (((size_t)b * 128) << 14);
  const char* Vb = (const char*)Vst + (((size_t)b * 128) << 15);

  if (w < 4) {
    // =========================== ENERGY ROLE ===========================
    const int ihE = w >> 1;            // 32-row half of the 64-row block
    const int jt  = w & 1;             // 16-j half of the 32-j tile
    bf16x8 qh[2][4], ql[2][4];
#pragma unroll
    for (int itq = 0; itq < 2; ++itq) {
      const size_t qb =
          (((size_t)b << 12) + n0 + ihE * 32 + itq * 16 + l15) * 128 + quad * 8;
#pragma unroll
      for (int ds = 0; ds < 4; ++ds) {
        qh[itq][ds] = *(const bf16x8*)(Qhi + qb + ds * 32);
        ql[itq][ds] = *(const bf16x8*)(Qlo + qb + ds * 32);
      }
    }
    // prologue: stage K(0) -> KL[0] (4 chunks of 1KB)
#pragma unroll
    for (int ch = 0; ch < 4; ++ch) {
      const int c = w + ch * 4;
      gld16(Kb + c * 1024 + lane * 16, &KL[0][c * 1024]);
    }
    float lpart[2] = {0.f, 0.f};

    for (int t = 0; t <= 128; ++t) {
      asm volatile("s_waitcnt vmcnt(0) lgkmcnt(0)" ::: "memory");
      __builtin_amdgcn_sched_barrier(0);
      __builtin_amdgcn_s_barrier();
      __builtin_amdgcn_sched_barrier(0);
      if (t < 128) {
        const int cur = t & 1;
        if (t < 127) {                 // stage K(t+1) -> KL[nxt]
          const char* src = Kb + ((size_t)(t + 1) << 14);
#pragma unroll
          for (int ch = 0; ch < 4; ++ch) {
            const int c = w + ch * 4;
            gld16(src + c * 1024 + lane * 16, &KL[cur ^ 1][c * 1024]);
          }
        }
        __builtin_amdgcn_sched_barrier(0);
        const int row = jt * 16 + l15;
        const unsigned rsw = (unsigned)(row & 7) << 4;
        const char* kb = &KL[cur][0];
        bf16x8 kh[4], kl[4];
#pragma unroll
        for (int ds = 0; ds < 4; ++ds) {
          const unsigned off = ((unsigned)(row * 256 + quad * 16 + ds * 64)) ^ rsw;
          kh[ds] = *(const bf16x8*)(kb + off);
          kl[ds] = *(const bf16x8*)(kb + 8192 + off);
        }
        f32x4 ea[2], eb[2], ec[2];
#pragma unroll
        for (int itq = 0; itq < 2; ++itq) {
          ea[itq] = (f32x4){0.f, 0.f, 0.f, 0.f};
          eb[itq] = (f32x4){0.f, 0.f, 0.f, 0.f};
          ec[itq] = (f32x4){0.f, 0.f, 0.f, 0.f};
        }
        __builtin_amdgcn_s_setprio(1);
#pragma unroll
        for (int ds = 0; ds < 4; ++ds)
#pragma unroll
          for (int itq = 0; itq < 2; ++itq) {
            ea[itq] = __builtin_amdgcn_mfma_f32_16x16x32_bf16(kh[ds], qh[itq][ds], ea[itq], 0, 0, 0);
            eb[itq] = __builtin_amdgcn_mfma_f32_16x16x32_bf16(kh[ds], ql[itq][ds], eb[itq], 0, 0, 0);
            ec[itq] = __builtin_amdgcn_mfma_f32_16x16x32_bf16(kl[ds], qh[itq][ds], ec[itq], 0, 0, 0);
          }
        __builtin_amdgcn_s_setprio(0);
#pragma unroll
        for (int itq = 0; itq < 2; ++itq) {
          const f32x4 e = (ea[itq] + eb[itq]) + ec[itq];
          const float p0 = __expf(e[0] - 32.0f);
          const float p1 = __expf(e[1] - 32.0f);
          const float p2 = __expf(e[2] - 32.0f);
          const float p3 = __expf(e[3] - 32.0f);
          const unsigned short u0 = f2bf(p0), u1 = f2bf(p1);
          const unsigned short u2 = f2bf(p2), u3 = f2bf(p3);
          lpart[itq] += (bf2f(u0) + bf2f(u1)) + (bf2f(u2) + bf2f(u3));
          unsigned int* dst = (unsigned int*)
              (&P[cur][ihE * 32 + itq * 16 + l15][jt * 16 + quad * 4]);
          dst[0] = (unsigned int)u0 | ((unsigned int)u1 << 16);
          dst[1] = (unsigned int)u2 | ((unsigned int)u3 << 16);
        }
      }
    }
    // l partials -> lstat
#pragma unroll
    for (int itq = 0; itq < 2; ++itq) {
      float lp = lpart[itq];
      lp += __shfl_xor(lp, 16, 64);
      lp += __shfl_xor(lp, 32, 64);
      if (quad == 0) lstat[jt][ihE * 2 + itq][l15] = lp;
    }
    __syncthreads();
    return;
  }

  // ============================= PV ROLE ==============================
  const int wv = w - 4;                // 64-channel slice owner
#pragma unroll
  for (int k = 0; k < 4; ++k) {
    const int c = wv * 4 + k;
    gld16(Vb + c * 1024 + lane * 16, &VL[0][c * 1024]);
  }
  f32x4 acc[4][4];                     // [ct][itv] = 64 regs
#pragma unroll
  for (int ct = 0; ct < 4; ++ct)
#pragma unroll
    for (int itv = 0; itv < 4; ++itv) acc[ct][itv] = (f32x4){0.f, 0.f, 0.f, 0.f};

  for (int t = 0; t <= 128; ++t) {
    if (t <= 127)
      asm volatile("s_waitcnt vmcnt(4)" ::: "memory");
    else
      asm volatile("s_waitcnt vmcnt(0)" ::: "memory");
    __builtin_amdgcn_sched_barrier(0);
    __builtin_amdgcn_s_barrier();
    __builtin_amdgcn_sched_barrier(0);
    if (t >= 1) {
      const int pb = (t - 1) & 1;
      bf16x8 pf[4];
#pragma unroll
      for (int itv = 0; itv < 4; ++itv)
        pf[itv] = *(const bf16x8*)(&P[pb][itv * 16 + l15][quad * 8]);
      const char* vb = &VL[pb][0];
      __builtin_amdgcn_s_setprio(1);
#pragma unroll
      for (int ct = 0; ct < 4; ++ct) {
        const int c = wv * 64 + ct * 16 + l15;
        const unsigned off =
            ((unsigned)(c * 64 + quad * 16)) ^ ((unsigned)(c & 7) << 4);
        const bf16x8 va = *(const bf16x8*)(vb + off);
#pragma unroll
        for (int itv = 0; itv < 4; ++itv)
          acc[ct][itv] = __builtin_amdgcn_mfma_f32_16x16x32_bf16(va, pf[itv], acc[ct][itv], 0, 0, 0);
      }
      __builtin_amdgcn_s_setprio(0);
      __builtin_amdgcn_sched_barrier(0);
    }
    if (t < 127) {                     // stage V(t+1) own slice (post-read)
      const char* src = Vb + ((size_t)(t + 1) << 15);
#pragma unroll
      for (int k = 0; k < 4; ++k) {
        const int c = wv * 4 + k;
        gld16(src + c * 1024 + lane * 16, &VL[(t + 1) & 1][c * 1024]);
      }
    }
  }
  __syncthreads();

  // ---- epilogue: out[c][n] = gamma*O/l + x for my 64-channel slice ----
  const float gv = gamF[0];
  float sc[4];
#pragma unroll
  for (int itv = 0; itv < 4; ++itv) {
    const float l = lstat[0][itv][l15] + lstat[1][itv][l15];
    sc[itv] = gv / l;
  }
#pragma unroll
  for (int ct = 0; ct < 4; ++ct)
#pragma unroll
    for (int r = 0; r < 4; ++r) {
      const int c_g = wv * 64 + ct * 16 + quad * 4 + r;
      const size_t brow = ((size_t)b * 512 + c_g) << 12;
#pragma unroll
      for (int itv = 0; itv < 4; ++itv) {
        const size_t addr = brow + n0 + itv * 16 + l15;
        const float o = sc[itv] * acc[ct][itv][r];
        if (fp32mode) {
          ((float*)outp)[addr] = o + ((const float*)x)[addr];
        } else {
          ((unsigned short*)outp)[addr] =
              f2bf(o + bf2f(((const unsigned short*)x)[addr]));
        }
      }
    }
}

extern "C" void kernel_launch(void* const* d_in, const int* in_sizes, int n_in,
                              void* d_out, int out_size, void* d_ws, size_t ws_size,
                              hipStream_t stream) {
  const void* x    = d_in[0];
  const void* dep  = d_in[1];
  const void* wq   = d_in[2];
  const void* bq   = d_in[3];
  const void* wqd  = d_in[4];
  const void* bqd  = d_in[5];
  const void* wk   = d_in[6];
  const void* bk   = d_in[7];
  const void* wkd  = d_in[8];
  const void* bkd  = d_in[9];
  const void* wv   = d_in[10];
  const void* bv   = d_in[11];
  const void* gam  = d_in[12];

  // ws: Whi(768K) Wlo(768K) Bcat gamF | @2M Qhi 4M | @6M Qlo 4M
  //     | @10M Kst 8M (tiled+swizzled) | @18M Vst 16M (tiled+swizzled)
  unsigned short* Whi = (unsigned short*)d_ws;
  unsigned short* Wlo = Whi + (size_t)768 * 512;
  float* Bcat = (float*)(Wlo + (size_t)768 * 512);
  float* gamF = Bcat + 768;
  unsigned short* Qhi = (unsigned short*)((char*)d_ws + ((size_t)2 << 20));
  unsigned short* Qlo = (unsigned short*)((char*)d_ws + ((size_t)6 << 20));
  unsigned short* Kst = (unsigned short*)((char*)d_ws + ((size_t)10 << 20));
  unsigned short* Vst = (unsigned short*)((char*)d_ws + ((size_t)18 << 20));

  prep_kernel<<<768, 256, 0, stream>>>(wq, bq, wqd, bqd, wk, bk, wkd, bkd,
                                       wv, bv, gam, x, Whi, Wlo, Bcat, gamF);
  proj_kernel<<<dim3(64, 4), 512, 0, stream>>>(x, dep, Whi, Wlo, Bcat,
                                               Qhi, Qlo, Kst, Vst);
  attn_kernel<<<256, 768, 0, stream>>>(Qhi, Qlo, Kst, Vst, x, gamF, d_out);
}

// Round 11
// 396.327 us; speedup vs baseline: 1.1858x; 1.1005x over previous
//
#include <hip/hip_runtime.h>

// ---------------------------------------------------------------------------
// PAM_Module_Dep: dual-modality position attention. B=4, C=512, N=4096, CQ=64.
// Round 16: proj SPLIT for instrumentation + regime change.
//   Rounds 10-15: six structurally different monolithic proj kernels all
//   201-240us vs ~30us work-floor models. Can't distinguish remaining causes
//   by theory -> split into two dispatches so rocprof per-dispatch timing
//   localizes the cost:
//     convert_kernel: x/dep -> pre-swizzled hi/lo bf16 tiles (Xst), pure
//       streaming (coalesced read + LDS transpose + coalesced uint4 write).
//     gemm_kernel: attn-style structure (the one that works): X staged via
//       global_load_lds into 64KB LDS, 2 blocks/CU = 16 waves/CU, 3 barriers
//       total, W 1-deep preload, direct stores.
//   ws guard: needs 100MB; falls back to round-15 monolith if ws is smaller.
// Math bit-identical everywhere (same f2bf split, chain order, layouts).
// attn: producer/consumer wave specialization (r10), unchanged.
// ---------------------------------------------------------------------------

typedef __attribute__((ext_vector_type(8))) short bf16x8;
typedef __attribute__((ext_vector_type(4))) float f32x4;

__device__ __forceinline__ float bf2f(unsigned short u) {
  return __builtin_bit_cast(float, (unsigned int)u << 16);
}
__device__ __forceinline__ unsigned short f2bf(float f) {
  unsigned int u = __builtin_bit_cast(unsigned int, f);
  u = u + 0x7fffu + ((u >> 16) & 1u);   // RNE
  return (unsigned short)(u >> 16);
}
__device__ __forceinline__ float bflo(unsigned int u) {
  return __builtin_bit_cast(float, u << 16);
}

// Async 16B/lane global->LDS DMA (wave writes ldsbase + lane*16).
__device__ __forceinline__ void gld16(const char* g, char* l) {
  __builtin_amdgcn_global_load_lds(
      (const __attribute__((address_space(1))) unsigned int*)g,
      (__attribute__((address_space(3))) unsigned int*)l, 16, 0, 0);
}

// Returns 1 if x looks like fp32 data, 0 if bf16. Wave-uniform, deterministic.
__device__ __forceinline__ int detect_fp32_mode(const void* xv) {
  const unsigned int* p = (const unsigned int*)xv;
  const int lane = threadIdx.x & 63;
  const unsigned int w0 = p[lane];
  const unsigned int w1 = p[64 + lane];
  int cnt = 0;
  const unsigned short us[4] = {
      (unsigned short)(w0 & 0xffffu), (unsigned short)(w0 >> 16),
      (unsigned short)(w1 & 0xffffu), (unsigned short)(w1 >> 16)};
#pragma unroll
  for (int h = 0; h < 4; ++h) {
    const float a = fabsf(bf2f(us[h]));
    cnt += (a > 9.0e-13f && a < 32.0f) ? 1 : 0;
  }
#pragma unroll
  for (int mm = 32; mm >= 1; mm >>= 1) cnt += __shfl_xor(cnt, mm, 64);
  return cnt < 220;
}

// ---------------------------------------------------------------------------
// prep: canonicalize weights into ws as split hi/lo bf16; biases+gamma fp32.
// ---------------------------------------------------------------------------
__global__ __launch_bounds__(256) void prep_kernel(
    const void* wq, const void* bq, const void* wqd, const void* bqd,
    const void* wk, const void* bk, const void* wkd, const void* bkd,
    const void* wv, const void* bv, const void* gam, const void* x,
    unsigned short* __restrict__ Whi, unsigned short* __restrict__ Wlo,
    float* __restrict__ Bcat, float* __restrict__ gamF)
{
  const int fp32mode = detect_fp32_mode(x);
  const int row = blockIdx.x;                    // 0..767
  const void* src; const void* bsrc; int srow;
  if (row < 64)       { src = wq;  bsrc = bq;  srow = row; }
  else if (row < 128) { src = wqd; bsrc = bqd; srow = row - 64; }
  else if (row < 192) { src = wk;  bsrc = bk;  srow = row - 128; }
  else if (row < 256) { src = wkd; bsrc = bkd; srow = row - 192; }
  else                { src = wv;  bsrc = bv;  srow = row - 256; }
  for (int c = threadIdx.x; c < 512; c += 256) {
    const float v = fp32mode ? ((const float*)src)[(size_t)srow * 512 + c]
                             : bf2f(((const unsigned short*)src)[(size_t)srow * 512 + c]);
    const unsigned short h = f2bf(v);
    Whi[(size_t)row * 512 + c] = h;
    Wlo[(size_t)row * 512 + c] = f2bf(v - bf2f(h));
  }
  if (threadIdx.x == 0) {
    Bcat[row] = fp32mode ? ((const float*)bsrc)[srow]
                         : bf2f(((const unsigned short*)bsrc)[srow]);
    if (row == 0)
      gamF[0] = fp32mode ? ((const float*)gam)[0]
                         : bf2f(((const unsigned short*)gam)[0]);
  }
}

// ---------------------------------------------------------------------------
// convert_kernel: x/dep -> Xst tiles, pure streaming.
// Xst tile (b,t,src): 64KB = hi plane 32KB | lo plane 32KB.
//   element (n,c): byte (n*1024 + 2c) ^ ((n&7)<<4) in plane.
// Block = one (b,t,src). Coalesced reads along n -> LDS [c][n] transpose ->
// convert -> coalesced uint4 writes along c.
// ---------------------------------------------------------------------------
__global__ __launch_bounds__(256) void convert_kernel(
    const void* __restrict__ x, const void* __restrict__ dep,
    unsigned short* __restrict__ Xst)
{
  __shared__ float XT[512][36];      // 73.7 KB, 16B-aligned rows
  const int fp32mode = detect_fp32_mode(x);
  const int tid = threadIdx.x;
  const int bid = blockIdx.x;        // 0..1023
  const int src = bid & 1, t = (bid >> 1) & 127, b = bid >> 8;
  const int n0 = t * 32;
  const void* s = src ? dep : x;
  const int crow = tid >> 3;         // 0..31 (+r*32)
  const int nf   = (tid & 7) * 4;    // n sub-offset (4 elems)

  float v[16][4];
  if (fp32mode) {
    const float* sp = (const float*)s;
#pragma unroll
    for (int r = 0; r < 16; ++r) {
      const int c = crow + r * 32;
      const float4 f4 = *(const float4*)(sp + (((size_t)b * 512 + c) << 12) + n0 + nf);
      v[r][0] = f4.x; v[r][1] = f4.y; v[r][2] = f4.z; v[r][3] = f4.w;
    }
  } else {
    const unsigned short* sp = (const unsigned short*)s;
#pragma unroll
    for (int r = 0; r < 16; ++r) {
      const int c = crow + r * 32;
      const uint2 u2 = *(const uint2*)(sp + (((size_t)b * 512 + c) << 12) + n0 + nf);
      v[r][0] = bflo(u2.x & 0xffffu); v[r][1] = bflo(u2.x >> 16);
      v[r][2] = bflo(u2.y & 0xffffu); v[r][3] = bflo(u2.y >> 16);
    }
  }
  __builtin_amdgcn_sched_barrier(0); // keep the 16 loads batched
#pragma unroll
  for (int r = 0; r < 16; ++r) {
    const int c = crow + r * 32;
#pragma unroll
    for (int k = 0; k < 4; ++k) XT[c][nf + k] = v[r][k];
  }
  __syncthreads();

  const int n  = tid & 31;           // output row
  const int cg = tid >> 5;           // 0..7 (64-c group)
  char* pb = (char*)Xst + ((((size_t)b * 128 + t) * 2 + src) << 16);
  const unsigned swz = (unsigned)(n & 7) << 4;
#pragma unroll
  for (int g = 0; g < 8; ++g) {
    unsigned short hi8[8], lo8[8];
#pragma unroll
    for (int i = 0; i < 8; ++i) {
      const float vv = XT[cg * 64 + g * 8 + i][n];
      const unsigned short h = f2bf(vv);
      hi8[i] = h;
      lo8[i] = f2bf(vv - bf2f(h));
    }
    const unsigned off = ((unsigned)(n * 1024 + 2 * (cg * 64 + g * 8))) ^ swz;
    *(uint4*)(pb + off)         = *(const uint4*)hi8;
    *(uint4*)(pb + 32768 + off) = *(const uint4*)lo8;
  }
}

// ---------------------------------------------------------------------------
// gemm tile: W from global (1-deep preload), X from swizzled LDS, direct
// global stores in the attn-expected layouts.
// ---------------------------------------------------------------------------
__device__ __forceinline__ void gtile(
    const unsigned short* __restrict__ Whi, const unsigned short* __restrict__ Wlo,
    const float* bsh, const char* __restrict__ XL, int fp32mode,
    int wrow0, int kind, int d0, int b, int t, int n0, int l15, int quad,
    unsigned short* __restrict__ Qhi, unsigned short* __restrict__ Qlo,
    unsigned short* __restrict__ Kst, unsigned short* __restrict__ Vst)
{
  f32x4 A0, A1, B0, B1, C0, C1;
#pragma unroll
  for (int r = 0; r < 4; ++r) {
    A0[r] = A1[r] = bsh[wrow0 + quad * 4 + r];
    B0[r] = B1[r] = C0[r] = C1[r] = 0.f;
  }
  const unsigned short* wh_p = Whi + (size_t)(wrow0 + l15) * 512 + quad * 8;
  const unsigned short* wl_p = Wlo + (size_t)(wrow0 + l15) * 512 + quad * 8;
  const unsigned base0 = (unsigned)(l15 * 1024 + quad * 16);
  const unsigned swz   = (unsigned)(l15 & 7) << 4;

  bf16x8 hc = *(const bf16x8*)(wh_p);
  bf16x8 lc;
  if (fp32mode) lc = *(const bf16x8*)(wl_p);

#pragma unroll 2
  for (int ks = 0; ks < 16; ++ks) {
    bf16x8 hn, ln;
    if (ks < 15) {
      hn = *(const bf16x8*)(wh_p + (ks + 1) * 32);
      if (fp32mode) ln = *(const bf16x8*)(wl_p + (ks + 1) * 32);
    }
    const unsigned o0 = (base0 + ks * 64) ^ swz;   // row l15
    const unsigned o1 = o0 + 16384;                // row 16+l15 (same XOR)
    const bf16x8 b0 = *(const bf16x8*)(XL + o0);
    const bf16x8 b1 = *(const bf16x8*)(XL + o1);
    A0 = __builtin_amdgcn_mfma_f32_16x16x32_bf16(hc, b0, A0, 0, 0, 0);
    A1 = __builtin_amdgcn_mfma_f32_16x16x32_bf16(hc, b1, A1, 0, 0, 0);
    if (fp32mode) {
      const bf16x8 c0 = *(const bf16x8*)(XL + 32768 + o0);
      const bf16x8 c1 = *(const bf16x8*)(XL + 32768 + o1);
      B0 = __builtin_amdgcn_mfma_f32_16x16x32_bf16(hc, c0, B0, 0, 0, 0);
      C0 = __builtin_amdgcn_mfma_f32_16x16x32_bf16(lc, b0, C0, 0, 0, 0);
      B1 = __builtin_amdgcn_mfma_f32_16x16x32_bf16(hc, c1, B1, 0, 0, 0);
      C1 = __builtin_amdgcn_mfma_f32_16x16x32_bf16(lc, b1, C1, 0, 0, 0);
    }
    if (ks < 15) { hc = hn; if (fp32mode) lc = ln; }
  }

  const f32x4 a0 = fp32mode ? (A0 + B0) + C0 : A0;
  const f32x4 a1 = fp32mode ? (A1 + B1) + C1 : A1;
#pragma unroll
  for (int ns = 0; ns < 2; ++ns) {
    const f32x4 acc = ns ? a1 : a0;
    const int j = ns * 16 + l15;                 // local row in tile
    if (kind <= 1) {                             // Q or K
      ushort4 h, l;
#pragma unroll
      for (int r = 0; r < 4; ++r) {
        const float f = acc[r];
        const unsigned short hh = f2bf(f);
        ((unsigned short*)&h)[r] = hh;
        ((unsigned short*)&l)[r] = f2bf(f - bf2f(hh));
      }
      if (kind == 0) {
        const size_t base = (((size_t)b << 12) + n0 + j) * 128 + d0 + quad * 4;
        *(ushort4*)(Qhi + base) = h;
        *(ushort4*)(Qlo + base) = l;
      } else {
        char* tb = (char*)Kst + (((size_t)b * 128 + t) << 14);
        const unsigned off =
            ((unsigned)(j * 256 + (d0 + quad * 4) * 2)) ^ ((unsigned)(j & 7) << 4);
        *(ushort4*)(tb + off) = h;
        *(ushort4*)(tb + 8192 + off) = l;
      }
    } else {                                     // V
      char* tb = (char*)Vst + (((size_t)b * 128 + t) << 15);
#pragma unroll
      for (int r = 0; r < 4; ++r) {
        const int c = d0 + quad * 4 + r;
        const unsigned off =
            ((unsigned)(c * 64 + j * 2)) ^ ((unsigned)(c & 7) << 4);
        *(unsigned short*)(tb + off) = f2bf(acc[r]);
      }
    }
  }
}

// ---------------------------------------------------------------------------
// gemm_kernel: 512 blocks (128 t x 4 b) x 512 thr (8 waves), 2 blocks/CU.
// Stage X-tile (64KB) via gld16, 1 sync; 5 W-tiles/wave; sync; stage dep
// tile; sync; 1 tile/wave. No other barriers — waves run free (16/CU).
// ---------------------------------------------------------------------------
__global__ __launch_bounds__(512, 4) void gemm_kernel(
    const void* __restrict__ x,
    const unsigned short* __restrict__ Whi, const unsigned short* __restrict__ Wlo,
    const float* __restrict__ Bcat, const unsigned short* __restrict__ Xst,
    unsigned short* __restrict__ Qhi, unsigned short* __restrict__ Qlo,
    unsigned short* __restrict__ Kst, unsigned short* __restrict__ Vst)
{
  __shared__ char XL[65536];           // hi 32K | lo 32K, swizzled
  __shared__ float bsh[768];
  const int fp32mode = detect_fp32_mode(x);
  const int tid  = threadIdx.x;
  const int lane = tid & 63;
  const int w    = tid >> 6;           // 0..7
  const int l15  = lane & 15;
  const int quad = lane >> 4;
  const int t  = blockIdx.x;           // n-tile
  const int b  = blockIdx.y;
  const int n0 = t * 32;

  for (int i = tid; i < 768; i += 512) bsh[i] = Bcat[i];

  const char* xsrc = (const char*)Xst + ((((size_t)b * 128 + t) * 2 + 0) << 16);
  const char* dsrc = xsrc + 65536;

#pragma unroll
  for (int i = 0; i < 8; ++i) {
    const int c8 = w + i * 8;
    gld16(xsrc + c8 * 1024 + lane * 16, XL + c8 * 1024);
  }
  __syncthreads();                     // drains vmcnt: X tile resident

  for (int i = 0; i < 5; ++i) {        // stage-1: 40 tiles, 5/wave
    const int rt = w + i * 8;
    int wrow0, kind, d0;
    if (rt < 4)      { wrow0 = rt * 16;             kind = 0; d0 = rt * 16; }
    else if (rt < 8) { wrow0 = 128 + (rt - 4) * 16; kind = 1; d0 = (rt - 4) * 16; }
    else             { wrow0 = 256 + (rt - 8) * 16; kind = 2; d0 = (rt - 8) * 16; }
    gtile(Whi, Wlo, bsh, XL, fp32mode, wrow0, kind, d0, b, t, n0, l15, quad,
          Qhi, Qlo, Kst, Vst);
  }
  __syncthreads();                     // all XL reads done

#pragma unroll
  for (int i = 0; i < 8; ++i) {
    const int c8 = w + i * 8;
    gld16(dsrc + c8 * 1024 + lane * 16, XL + c8 * 1024);
  }
  __syncthreads();                     // dep tile resident

  {                                    // stage-2: 8 tiles, 1/wave
    const int kind  = (w < 4) ? 0 : 1;
    const int wrow0 = (w < 4) ? 64 + w * 16 : 192 + (w - 4) * 16;
    const int d0    = 64 + (w & 3) * 16;
    gtile(Whi, Wlo, bsh, XL, fp32mode, wrow0, kind, d0, b, t, n0, l15, quad,
          Qhi, Qlo, Kst, Vst);
  }
}

// ---------------------------------------------------------------------------
// FALLBACK monolithic proj (round-15), used only if ws_size < 100MB.
// ---------------------------------------------------------------------------
__device__ __forceinline__ void stage_X(
    const void* __restrict__ src, int fp32mode, int b, int n0,
    int cbase, int nn,
    unsigned short* __restrict__ Xhi, unsigned short* __restrict__ Xlo)
{
  float v[8][4];
  if (fp32mode) {
    const float* s = (const float*)src;
#pragma unroll
    for (int r = 0; r < 8; ++r) {
      const int c = cbase + r * 64;
      const float4 f4 = *(const float4*)(s + (((size_t)b * 512 + c) << 12) + n0 + nn);
      v[r][0] = f4.x; v[r][1] = f4.y; v[r][2] = f4.z; v[r][3] = f4.w;
    }
  } else {
    const unsigned short* s = (const unsigned short*)src;
#pragma unroll
    for (int r = 0; r < 8; ++r) {
      const int c = cbase + r * 64;
      const uint2 u2 = *(const uint2*)(s + (((size_t)b * 512 + c) << 12) + n0 + nn);
      v[r][0] = bflo(u2.x & 0xffffu); v[r][1] = bflo(u2.x >> 16);
      v[r][2] = bflo(u2.y & 0xffffu); v[r][3] = bflo(u2.y >> 16);
    }
  }
  __builtin_amdgcn_sched_barrier(0);
#pragma unroll
  for (int r = 0; r < 8; ++r) {
    const int c = cbase + r * 64;
#pragma unroll
    for (int k = 0; k < 4; ++k) {
      const unsigned short h = f2bf(v[r][k]);
      Xhi[(nn + k) * 522 + c] = h;
      Xlo[(nn + k) * 522 + c] = f2bf(v[r][k] - bf2f(h));
    }
  }
}

__device__ __forceinline__ void do_tile_c(
    const unsigned short* __restrict__ Whi, const unsigned short* __restrict__ Wlo,
    const float* bsh,
    const unsigned short* Xhi, const unsigned short* Xlo, int fp32mode,
    int wrow0, int kind, int d0,
    int l15, int quad,
    char* __restrict__ QT, char* __restrict__ KT, char* __restrict__ VT)
{
  f32x4 A0, A1, B0, B1, C0, C1;
#pragma unroll
  for (int r = 0; r < 4; ++r) {
    A0[r] = A1[r] = bsh[wrow0 + quad * 4 + r];
    B0[r] = B1[r] = C0[r] = C1[r] = 0.f;
  }
  const unsigned short* wh_p = Whi + (size_t)(wrow0 + l15) * 512 + quad * 8;
  const unsigned short* wl_p = Wlo + (size_t)(wrow0 + l15) * 512 + quad * 8;
  const unsigned short* x0h = Xhi + l15 * 522 + quad * 8;
  const unsigned short* x1h = Xhi + (16 + l15) * 522 + quad * 8;
  const unsigned short* x0l = Xlo + l15 * 522 + quad * 8;
  const unsigned short* x1l = Xlo + (16 + l15) * 522 + quad * 8;

  bf16x8 hc = *(const bf16x8*)(wh_p);
  bf16x8 lc;
  if (fp32mode) lc = *(const bf16x8*)(wl_p);

#pragma unroll 2
  for (int ks = 0; ks < 16; ++ks) {
    bf16x8 hn, ln;
    if (ks < 15) {
      hn = *(const bf16x8*)(wh_p + (ks + 1) * 32);
      if (fp32mode) ln = *(const bf16x8*)(wl_p + (ks + 1) * 32);
    }
    const int o = ks * 32;
    const bf16x8 b0 = *(const bf16x8*)(x0h + o);
    const bf16x8 b1 = *(const bf16x8*)(x1h + o);
    A0 = __builtin_amdgcn_mfma_f32_16x16x32_bf16(hc, b0, A0, 0, 0, 0);
    A1 = __builtin_amdgcn_mfma_f32_16x16x32_bf16(hc, b1, A1, 0, 0, 0);
    if (fp32mode) {
      const bf16x8 c0 = *(const bf16x8*)(x0l + o);
      const bf16x8 c1 = *(const bf16x8*)(x1l + o);
      B0 = __builtin_amdgcn_mfma_f32_16x16x32_bf16(hc, c0, B0, 0, 0, 0);
      C0 = __builtin_amdgcn_mfma_f32_16x16x32_bf16(lc, b0, C0, 0, 0, 0);
      B1 = __builtin_amdgcn_mfma_f32_16x16x32_bf16(hc, c1, B1, 0, 0, 0);
      C1 = __builtin_amdgcn_mfma_f32_16x16x32_bf16(lc, b1, C1, 0, 0, 0);
    }
    if (ks < 15) { hc = hn; if (fp32mode) lc = ln; }
  }

  const f32x4 a0 = fp32mode ? (A0 + B0) + C0 : A0;
  const f32x4 a1 = fp32mode ? (A1 + B1) + C1 : A1;
#pragma unroll
  for (int ns = 0; ns < 2; ++ns) {
    const f32x4 acc = ns ? a1 : a0;
    const int n = ns * 16 + l15;
    if (kind <= 1) {
      ushort4 h, l;
#pragma unroll
      for (int r = 0; r < 4; ++r) {
        const float f = acc[r];
        const unsigned short hh = f2bf(f);
        ((unsigned short*)&h)[r] = hh;
        ((unsigned short*)&l)[r] = f2bf(f - bf2f(hh));
      }
      const unsigned lin = (unsigned)(n * 256 + (d0 + quad * 4) * 2);
      if (kind == 0) {
        *(ushort4*)(QT + lin) = h;
        *(ushort4*)(QT + 8192 + lin) = l;
      } else {
        const unsigned off = lin ^ ((unsigned)(n & 7) << 4);
        *(ushort4*)(KT + off) = h;
        *(ushort4*)(KT + 8192 + off) = l;
      }
    } else {
#pragma unroll
      for (int r = 0; r < 4; ++r) {
        const int c = d0 + quad * 4 + r;
        const unsigned off =
            ((unsigned)(c * 64 + n * 2)) ^ ((unsigned)(c & 7) << 4);
        *(unsigned short*)(VT + off) = f2bf(acc[r]);
      }
    }
  }
}

__global__ __launch_bounds__(512, 2) void proj_kernel(
    const void* __restrict__ x, const void* __restrict__ dep,
    const unsigned short* __restrict__ Whi, const unsigned short* __restrict__ Wlo,
    const float* __restrict__ Bcat,
    unsigned short* __restrict__ Qhi, unsigned short* __restrict__ Qlo,
    unsigned short* __restrict__ Kst, unsigned short* __restrict__ Vst)
{
  __shared__ unsigned short Xhi[32 * 522];
  __shared__ unsigned short Xlo[32 * 522];
  __shared__ char QT[16384];
  __shared__ char KT[16384];
  __shared__ char VT[32768];
  __shared__ float bsh[768];
  const int fp32mode = detect_fp32_mode(x);
  const int tid  = threadIdx.x;
  const int lane = tid & 63;
  const int w    = tid >> 6;
  const int l15  = lane & 15;
  const int quad = lane >> 4;
  const int b  = blockIdx.y;
  const int cbase = tid >> 3;
  const int nn    = (tid & 7) * 4;

  for (int i = tid; i < 768; i += 512) bsh[i] = Bcat[i];

  for (int rep = 0; rep < 2; ++rep) {
    const int t  = blockIdx.x + rep * 64;
    const int n0 = t * 32;
    stage_X(x, fp32mode, b, n0, cbase, nn, Xhi, Xlo);
    __syncthreads();
    for (int rt = w; rt < 40; rt += 8) {
      int wrow0, kind, d0;
      if (rt < 4)      { wrow0 = rt * 16;             kind = 0; d0 = rt * 16; }
      else if (rt < 8) { wrow0 = 128 + (rt - 4) * 16; kind = 1; d0 = (rt - 4) * 16; }
      else             { wrow0 = 256 + (rt - 8) * 16; kind = 2; d0 = (rt - 8) * 16; }
      do_tile_c(Whi, Wlo, bsh, Xhi, Xlo, fp32mode, wrow0, kind, d0,
                l15, quad, QT, KT, VT);
    }
    __syncthreads();
    {
      char* vdst = (char*)Vst + (((size_t)b * 128 + t) << 15);
#pragma unroll
      for (int i = 0; i < 4; ++i) {
        const int off = i * 8192 + tid * 16;
        *(uint4*)(vdst + off) = *(const uint4*)(VT + off);
      }
    }
    stage_X(dep, fp32mode, b, n0, cbase, nn, Xhi, Xlo);
    __syncthreads();
    {
      const int rt = w;
      const int kind  = (rt < 4) ? 0 : 1;
      const int wrow0 = (rt < 4) ? 64 + rt * 16 : 192 + (rt - 4) * 16;
      const int d0    = 64 + (rt & 3) * 16;
      do_tile_c(Whi, Wlo, bsh, Xhi, Xlo, fp32mode, wrow0, kind, d0,
                l15, quad, QT, KT, VT);
    }
    __syncthreads();
    {
      char* kdst = (char*)Kst + (((size_t)b * 128 + t) << 14);
#pragma unroll
      for (int i = 0; i < 2; ++i) {
        const int off = i * 8192 + tid * 16;
        *(uint4*)(kdst + off) = *(const uint4*)(KT + off);
      }
      const size_t qoff = ((((size_t)b << 12) + (size_t)t * 32) * 128) * 2;
      *(uint4*)((char*)Qhi + qoff + tid * 16) = *(const uint4*)(QT + tid * 16);
      *(uint4*)((char*)Qlo + qoff + tid * 16) = *(const uint4*)(QT + 8192 + tid * 16);
    }
    __syncthreads();
  }
}

// ---------------------------------------------------------------------------
// Producer/consumer flash attention (unchanged from round 10).
// ---------------------------------------------------------------------------
__global__ __launch_bounds__(768, 3) void attn_kernel(
    const unsigned short* __restrict__ Qhi, const unsigned short* __restrict__ Qlo,
    const unsigned short* __restrict__ Kst, const unsigned short* __restrict__ Vst,
    const void* __restrict__ x, const float* __restrict__ gamF,
    void* __restrict__ outp)
{
  __shared__ char KL[2][16384];
  __shared__ char VL[2][32768];
  __shared__ unsigned short P[2][64][40];
  __shared__ float lstat[2][4][16];

  const int fp32mode = detect_fp32_mode(x);
  const int tid  = threadIdx.x;
  const int lane = tid & 63;
  const int w    = tid >> 6;
  const int l15  = lane & 15;
  const int quad = lane >> 4;
  const int id   = blockIdx.x;
  const int b    = (id >> 1) & 3;
  const int n0   = (((id >> 3) << 1) | (id & 1)) * 64;

  asm volatile("" :: "v"(fp32mode) : "memory");

  const char* Kb = (const char*)Kst + (((size_t)b * 128) << 14);
  const char* Vb = (const char*)Vst + (((size_t)b * 128) << 15);

  if (w < 4) {
    const int ihE = w >> 1;
    const int jt  = w & 1;
    bf16x8 qh[2][4], ql[2][4];
#pragma unroll
    for (int itq = 0; itq < 2; ++itq) {
      const size_t qb =
          (((size_t)b << 12) + n0 + ihE * 32 + itq * 16 + l15) * 128 + quad * 8;
#pragma unroll
      for (int ds = 0; ds < 4; ++ds) {
        qh[itq][ds] = *(const bf16x8*)(Qhi + qb + ds * 32);
        ql[itq][ds] = *(const bf16x8*)(Qlo + qb + ds * 32);
      }
    }
#pragma unroll
    for (int ch = 0; ch < 4; ++ch) {
      const int c = w + ch * 4;
      gld16(Kb + c * 1024 + lane * 16, &KL[0][c * 1024]);
    }
    float lpart[2] = {0.f, 0.f};

    for (int t = 0; t <= 128; ++t) {
      asm volatile("s_waitcnt vmcnt(0) lgkmcnt(0)" ::: "memory");
      __builtin_amdgcn_sched_barrier(0);
      __builtin_amdgcn_s_barrier();
      __builtin_amdgcn_sched_barrier(0);
      if (t < 128) {
        const int cur = t & 1;
        if (t < 127) {
          const char* src = Kb + ((size_t)(t + 1) << 14);
#pragma unroll
          for (int ch = 0; ch < 4; ++ch) {
            const int c = w + ch * 4;
            gld16(src + c * 1024 + lane * 16, &KL[cur ^ 1][c * 1024]);
          }
        }
        __builtin_amdgcn_sched_barrier(0);
        const int row = jt * 16 + l15;
        const unsigned rsw = (unsigned)(row & 7) << 4;
        const char* kb = &KL[cur][0];
        bf16x8 kh[4], kl[4];
#pragma unroll
        for (int ds = 0; ds < 4; ++ds) {
          const unsigned off = ((unsigned)(row * 256 + quad * 16 + ds * 64)) ^ rsw;
          kh[ds] = *(const bf16x8*)(kb + off);
          kl[ds] = *(const bf16x8*)(kb + 8192 + off);
        }
        f32x4 ea[2], eb[2], ec[2];
#pragma unroll
        for (int itq = 0; itq < 2; ++itq) {
          ea[itq] = (f32x4){0.f, 0.f, 0.f, 0.f};
          eb[itq] = (f32x4){0.f, 0.f, 0.f, 0.f};
          ec[itq] = (f32x4){0.f, 0.f, 0.f, 0.f};
        }
        __builtin_amdgcn_s_setprio(1);
#pragma unroll
        for (int ds = 0; ds < 4; ++ds)
#pragma unroll
          for (int itq = 0; itq < 2; ++itq) {
            ea[itq] = __builtin_amdgcn_mfma_f32_16x16x32_bf16(kh[ds], qh[itq][ds], ea[itq], 0, 0, 0);
            eb[itq] = __builtin_amdgcn_mfma_f32_16x16x32_bf16(kh[ds], ql[itq][ds], eb[itq], 0, 0, 0);
            ec[itq] = __builtin_amdgcn_mfma_f32_16x16x32_bf16(kl[ds], qh[itq][ds], ec[itq], 0, 0, 0);
          }
        __builtin_amdgcn_s_setprio(0);
#pragma unroll
        for (int itq = 0; itq < 2; ++itq) {
          const f32x4 e = (ea[itq] + eb[itq]) + ec[itq];
          const float p0 = __expf(e[0] - 32.0f);
          const float p1 = __expf(e[1] - 32.0f);
          const float p2 = __expf(e[2] - 32.0f);
          const float p3 = __expf(e[3] - 32.0f);
          const unsigned short u0 = f2bf(p0), u1 = f2bf(p1);
          const unsigned short u2 = f2bf(p2), u3 = f2bf(p3);
          lpart[itq] += (bf2f(u0) + bf2f(u1)) + (bf2f(u2) + bf2f(u3));
          unsigned int* dst = (unsigned int*)
              (&P[cur][ihE * 32 + itq * 16 + l15][jt * 16 + quad * 4]);
          dst[0] = (unsigned int)u0 | ((unsigned int)u1 << 16);
          dst[1] = (unsigned int)u2 | ((unsigned int)u3 << 16);
        }
      }
    }
#pragma unroll
    for (int itq = 0; itq < 2; ++itq) {
      float lp = lpart[itq];
      lp += __shfl_xor(lp, 16, 64);
      lp += __shfl_xor(lp, 32, 64);
      if (quad == 0) lstat[jt][ihE * 2 + itq][l15] = lp;
    }
    __syncthreads();
    return;
  }

  const int wv = w - 4;
#pragma unroll
  for (int k = 0; k < 4; ++k) {
    const int c = wv * 4 + k;
    gld16(Vb + c * 1024 + lane * 16, &VL[0][c * 1024]);
  }
  f32x4 acc[4][4];
#pragma unroll
  for (int ct = 0; ct < 4; ++ct)
#pragma unroll
    for (int itv = 0; itv < 4; ++itv) acc[ct][itv] = (f32x4){0.f, 0.f, 0.f, 0.f};

  for (int t = 0; t <= 128; ++t) {
    if (t <= 127)
      asm volatile("s_waitcnt vmcnt(4)" ::: "memory");
    else
      asm volatile("s_waitcnt vmcnt(0)" ::: "memory");
    __builtin_amdgcn_sched_barrier(0);
    __builtin_amdgcn_s_barrier();
    __builtin_amdgcn_sched_barrier(0);
    if (t >= 1) {
      const int pb = (t - 1) & 1;
      bf16x8 pf[4];
#pragma unroll
      for (int itv = 0; itv < 4; ++itv)
        pf[itv] = *(const bf16x8*)(&P[pb][itv * 16 + l15][quad * 8]);
      const char* vb = &VL[pb][0];
      __builtin_amdgcn_s_setprio(1);
#pragma unroll
      for (int ct = 0; ct < 4; ++ct) {
        const int c = wv * 64 + ct * 16 + l15;
        const unsigned off =
            ((unsigned)(c * 64 + quad * 16)) ^ ((unsigned)(c & 7) << 4);
        const bf16x8 va = *(const bf16x8*)(vb + off);
#pragma unroll
        for (int itv = 0; itv < 4; ++itv)
          acc[ct][itv] = __builtin_amdgcn_mfma_f32_16x16x32_bf16(va, pf[itv], acc[ct][itv], 0, 0, 0);
      }
      __builtin_amdgcn_s_setprio(0);
      __builtin_amdgcn_sched_barrier(0);
    }
    if (t < 127) {
      const char* src = Vb + ((size_t)(t + 1) << 15);
#pragma unroll
      for (int k = 0; k < 4; ++k) {
        const int c = wv * 4 + k;
        gld16(src + c * 1024 + lane * 16, &VL[(t + 1) & 1][c * 1024]);
      }
    }
  }
  __syncthreads();

  const float gv = gamF[0];
  float sc[4];
#pragma unroll
  for (int itv = 0; itv < 4; ++itv) {
    const float l = lstat[0][itv][l15] + lstat[1][itv][l15];
    sc[itv] = gv / l;
  }
#pragma unroll
  for (int ct = 0; ct < 4; ++ct)
#pragma unroll
    for (int r = 0; r < 4; ++r) {
      const int c_g = wv * 64 + ct * 16 + quad * 4 + r;
      const size_t brow = ((size_t)b * 512 + c_g) << 12;
#pragma unroll
      for (int itv = 0; itv < 4; ++itv) {
        const size_t addr = brow + n0 + itv * 16 + l15;
        const float o = sc[itv] * acc[ct][itv][r];
        if (fp32mode) {
          ((float*)outp)[addr] = o + ((const float*)x)[addr];
        } else {
          ((unsigned short*)outp)[addr] =
              f2bf(o + bf2f(((const unsigned short*)x)[addr]));
        }
      }
    }
}

extern "C" void kernel_launch(void* const* d_in, const int* in_sizes, int n_in,
                              void* d_out, int out_size, void* d_ws, size_t ws_size,
                              hipStream_t stream) {
  const void* x    = d_in[0];
  const void* dep  = d_in[1];
  const void* wq   = d_in[2];
  const void* bq   = d_in[3];
  const void* wqd  = d_in[4];
  const void* bqd  = d_in[5];
  const void* wk   = d_in[6];
  const void* bk   = d_in[7];
  const void* wkd  = d_in[8];
  const void* bkd  = d_in[9];
  const void* wv   = d_in[10];
  const void* bv   = d_in[11];
  const void* gam  = d_in[12];

  // ws: Whi/Wlo/Bcat/gamF | @2M Qhi 4M | @6M Qlo 4M | @10M Kst 8M
  //     | @18M Vst 16M | @36M Xst 64M (split path only; total 100M)
  unsigned short* Whi = (unsigned short*)d_ws;
  unsigned short* Wlo = Whi + (size_t)768 * 512;
  float* Bcat = (float*)(Wlo + (size_t)768 * 512);
  float* gamF = Bcat + 768;
  unsigned short* Qhi = (unsigned short*)((char*)d_ws + ((size_t)2 << 20));
  unsigned short* Qlo = (unsigned short*)((char*)d_ws + ((size_t)6 << 20));
  unsigned short* Kst = (unsigned short*)((char*)d_ws + ((size_t)10 << 20));
  unsigned short* Vst = (unsigned short*)((char*)d_ws + ((size_t)18 << 20));
  unsigned short* Xst = (unsigned short*)((char*)d_ws + ((size_t)36 << 20));

  prep_kernel<<<768, 256, 0, stream>>>(wq, bq, wqd, bqd, wk, bk, wkd, bkd,
                                       wv, bv, gam, x, Whi, Wlo, Bcat, gamF);
  if (ws_size >= ((size_t)100 << 20)) {
    convert_kernel<<<1024, 256, 0, stream>>>(x, dep, Xst);
    gemm_kernel<<<dim3(128, 4), 512, 0, stream>>>(x, Whi, Wlo, Bcat, Xst,
                                                  Qhi, Qlo, Kst, Vst);
  } else {
    proj_kernel<<<dim3(64, 4), 512, 0, stream>>>(x, dep, Whi, Wlo, Bcat,
                                                 Qhi, Qlo, Kst, Vst);
  }
  attn_kernel<<<256, 768, 0, stream>>>(Qhi, Qlo, Kst, Vst, x, gamF, d_out);
}